// Round 1
// baseline (10823.502 us; speedup 1.0000x reference)
//
#include <hip/hip_runtime.h>
#include <math.h>

#define NEG_SLOPE 0.2f

__device__ __forceinline__ unsigned fenc(float f){
  unsigned u = __float_as_uint(f);
  return (u & 0x80000000u) ? ~u : (u | 0x80000000u);
}
__device__ __forceinline__ float fdec(unsigned k){
  return (k & 0x80000000u) ? __uint_as_float(k & 0x7FFFFFFFu) : __uint_as_float(~k);
}
__device__ __forceinline__ float lrelu(float x){ return x >= 0.f ? x : NEG_SLOPE * x; }

// ---------------- GEMM1: h1 = x @ W1, [N,256] x [256,64] -> [N,64] ----------------
__global__ void k_gemm1(const float* __restrict__ x, const float* __restrict__ W,
                        float* __restrict__ h, int N){
  int col = threadIdx.x & 63;       // 64 output cols
  int rq  = threadIdx.x >> 6;      // 4 row-groups per block
  int r0  = blockIdx.x * 16 + rq * 4;
  if (r0 >= N) return;
  int r1 = min(r0 + 1, N - 1), r2 = min(r0 + 2, N - 1), r3 = min(r0 + 3, N - 1);
  const float* x0 = x + (size_t)r0 * 256;
  const float* x1 = x + (size_t)r1 * 256;
  const float* x2 = x + (size_t)r2 * 256;
  const float* x3 = x + (size_t)r3 * 256;
  float a0 = 0.f, a1 = 0.f, a2 = 0.f, a3 = 0.f;
  #pragma unroll 8
  for (int k = 0; k < 256; k++){
    float w = W[k * 64 + col];
    a0 = fmaf(x0[k], w, a0);
    a1 = fmaf(x1[k], w, a1);
    a2 = fmaf(x2[k], w, a2);
    a3 = fmaf(x3[k], w, a3);
  }
  h[(size_t)r0 * 64 + col] = a0;
  if (r0 + 1 < N) h[(size_t)(r0 + 1) * 64 + col] = a1;
  if (r0 + 2 < N) h[(size_t)(r0 + 2) * 64 + col] = a2;
  if (r0 + 3 < N) h[(size_t)(r0 + 3) * 64 + col] = a3;
}

// ---------------- alpha1: per (node, head) dot over C=8 ----------------
__global__ void k_alpha1(const float* __restrict__ h, const float* __restrict__ asrc,
                         const float* __restrict__ adst, float* __restrict__ as_,
                         float* __restrict__ ad_, int N){
  int i = blockIdx.x * blockDim.x + threadIdx.x;   // over N*8
  if (i >= N * 8) return;
  int hd = i & 7;
  const float* hp = h + (size_t)(i >> 3) * 64 + hd * 8;
  float s = 0.f, d = 0.f;
  #pragma unroll
  for (int c = 0; c < 8; c++){
    float v = hp[c];
    s = fmaf(v, asrc[hd * 8 + c], s);
    d = fmaf(v, adst[hd * 8 + c], d);
  }
  as_[i] = s; ad_[i] = d;
}

// ---------------- edge pass A (layer1): segment max over dst ----------------
__global__ void k_emax1(const int* __restrict__ ei, int E, int N,
                        const float* __restrict__ as_, const float* __restrict__ ad_,
                        unsigned* __restrict__ m){
  int e = blockIdx.x * blockDim.x + threadIdx.x;
  if (e >= E + N) return;
  int s, d;
  if (e < E){ s = ei[e]; d = ei[E + e]; } else { s = e - E; d = s; }
  const float4* ap = (const float4*)(as_ + (size_t)s * 8);
  const float4* bp = (const float4*)(ad_ + (size_t)d * 8);
  float4 A0 = ap[0], A1 = ap[1], B0 = bp[0], B1 = bp[1];
  unsigned* md = m + (size_t)d * 8;
  atomicMax(md + 0, fenc(lrelu(A0.x + B0.x)));
  atomicMax(md + 1, fenc(lrelu(A0.y + B0.y)));
  atomicMax(md + 2, fenc(lrelu(A0.z + B0.z)));
  atomicMax(md + 3, fenc(lrelu(A0.w + B0.w)));
  atomicMax(md + 4, fenc(lrelu(A1.x + B1.x)));
  atomicMax(md + 5, fenc(lrelu(A1.y + B1.y)));
  atomicMax(md + 6, fenc(lrelu(A1.z + B1.z)));
  atomicMax(md + 7, fenc(lrelu(A1.w + B1.w)));
}

// ---------------- edge pass B (layer1): denom = segment sum of exp ----------------
__global__ void k_esum1(const int* __restrict__ ei, int E, int N,
                        const float* __restrict__ as_, const float* __restrict__ ad_,
                        const unsigned* __restrict__ m, float* __restrict__ den){
  int e = blockIdx.x * blockDim.x + threadIdx.x;
  if (e >= E + N) return;
  int s, d;
  if (e < E){ s = ei[e]; d = ei[E + e]; } else { s = e - E; d = s; }
  const float4* ap = (const float4*)(as_ + (size_t)s * 8);
  const float4* bp = (const float4*)(ad_ + (size_t)d * 8);
  float4 A0 = ap[0], A1 = ap[1], B0 = bp[0], B1 = bp[1];
  const unsigned* md = m + (size_t)d * 8;
  float* dd = den + (size_t)d * 8;
  atomicAdd(dd + 0, __expf(lrelu(A0.x + B0.x) - fdec(md[0])));
  atomicAdd(dd + 1, __expf(lrelu(A0.y + B0.y) - fdec(md[1])));
  atomicAdd(dd + 2, __expf(lrelu(A0.z + B0.z) - fdec(md[2])));
  atomicAdd(dd + 3, __expf(lrelu(A0.w + B0.w) - fdec(md[3])));
  atomicAdd(dd + 4, __expf(lrelu(A1.x + B1.x) - fdec(md[4])));
  atomicAdd(dd + 5, __expf(lrelu(A1.y + B1.y) - fdec(md[5])));
  atomicAdd(dd + 6, __expf(lrelu(A1.z + B1.z) - fdec(md[6])));
  atomicAdd(dd + 7, __expf(lrelu(A1.w + B1.w) - fdec(md[7])));
}

// ---------------- edge pass C (layer1): scatter msg = h1[src] * alpha ----------------
__global__ void k_escat1(const int* __restrict__ ei, int E, int N,
                         const float* __restrict__ as_, const float* __restrict__ ad_,
                         const unsigned* __restrict__ m, const float* __restrict__ den,
                         const float* __restrict__ h1, float* __restrict__ out){
  int e = blockIdx.x * blockDim.x + threadIdx.x;
  if (e >= E + N) return;
  int s, d;
  if (e < E){ s = ei[e]; d = ei[E + e]; } else { s = e - E; d = s; }
  const float* asp = as_ + (size_t)s * 8;
  const float* adp = ad_ + (size_t)d * 8;
  const unsigned* md = m + (size_t)d * 8;
  const float* dd = den + (size_t)d * 8;
  const float4* hp = (const float4*)(h1 + (size_t)s * 64);
  float* od = out + (size_t)d * 64;
  #pragma unroll
  for (int hh = 0; hh < 8; hh++){
    float v = lrelu(asp[hh] + adp[hh]);
    float alpha = __expf(v - fdec(md[hh])) / dd[hh];
    float4 p0 = hp[hh * 2], p1 = hp[hh * 2 + 1];
    atomicAdd(od + hh * 8 + 0, p0.x * alpha);
    atomicAdd(od + hh * 8 + 1, p0.y * alpha);
    atomicAdd(od + hh * 8 + 2, p0.z * alpha);
    atomicAdd(od + hh * 8 + 3, p0.w * alpha);
    atomicAdd(od + hh * 8 + 4, p1.x * alpha);
    atomicAdd(od + hh * 8 + 5, p1.y * alpha);
    atomicAdd(od + hh * 8 + 6, p1.z * alpha);
    atomicAdd(od + hh * 8 + 7, p1.w * alpha);
  }
}

// ---------------- bias + relu in place on out1 [N,64] ----------------
__global__ void k_bias_relu(float* __restrict__ o, const float* __restrict__ b, size_t total){
  size_t i = (size_t)blockIdx.x * blockDim.x + threadIdx.x;
  if (i >= total) return;
  float v = o[i] + b[i & 63];
  o[i] = v > 0.f ? v : 0.f;
}

// ---------------- GEMM2: h2 = out1 @ W2, [N,64] x [64,40] -> [N,40] ----------------
__global__ void k_gemm2(const float* __restrict__ in, const float* __restrict__ W,
                        float* __restrict__ h2, int N){
  int i = blockIdx.x * blockDim.x + threadIdx.x;
  if (i >= N * 40) return;
  int c = i % 40, n = i / 40;
  const float* r = in + (size_t)n * 64;
  float acc = 0.f;
  #pragma unroll 8
  for (int k = 0; k < 64; k++) acc = fmaf(r[k], W[k * 40 + c], acc);
  h2[i] = acc;
}

// ---------------- alpha2: per node dot over 40 ----------------
__global__ void k_alpha2(const float* __restrict__ h2, const float* __restrict__ asrc,
                         const float* __restrict__ adst, float* __restrict__ as_,
                         float* __restrict__ ad_, int N){
  int n = blockIdx.x * blockDim.x + threadIdx.x;
  if (n >= N) return;
  const float* r = h2 + (size_t)n * 40;
  float s = 0.f, d = 0.f;
  #pragma unroll 8
  for (int c = 0; c < 40; c++){
    float v = r[c];
    s = fmaf(v, asrc[c], s);
    d = fmaf(v, adst[c], d);
  }
  as_[n] = s; ad_[n] = d;
}

// ---------------- edge passes layer2 (H=1) ----------------
__global__ void k_emax2(const int* __restrict__ ei, int E, int N,
                        const float* __restrict__ as_, const float* __restrict__ ad_,
                        unsigned* __restrict__ m){
  int e = blockIdx.x * blockDim.x + threadIdx.x;
  if (e >= E + N) return;
  int s, d;
  if (e < E){ s = ei[e]; d = ei[E + e]; } else { s = e - E; d = s; }
  atomicMax(m + d, fenc(lrelu(as_[s] + ad_[d])));
}

__global__ void k_esum2(const int* __restrict__ ei, int E, int N,
                        const float* __restrict__ as_, const float* __restrict__ ad_,
                        const unsigned* __restrict__ m, float* __restrict__ den){
  int e = blockIdx.x * blockDim.x + threadIdx.x;
  if (e >= E + N) return;
  int s, d;
  if (e < E){ s = ei[e]; d = ei[E + e]; } else { s = e - E; d = s; }
  atomicAdd(den + d, __expf(lrelu(as_[s] + ad_[d]) - fdec(m[d])));
}

__global__ void k_escat2(const int* __restrict__ ei, int E, int N,
                         const float* __restrict__ as_, const float* __restrict__ ad_,
                         const unsigned* __restrict__ m, const float* __restrict__ den,
                         const float* __restrict__ h2, float* __restrict__ out){
  int e = blockIdx.x * blockDim.x + threadIdx.x;
  if (e >= E + N) return;
  int s, d;
  if (e < E){ s = ei[e]; d = ei[E + e]; } else { s = e - E; d = s; }
  float alpha = __expf(lrelu(as_[s] + ad_[d]) - fdec(m[d])) / den[d];
  const float4* hp = (const float4*)(h2 + (size_t)s * 40);
  float* od = out + (size_t)d * 40;
  #pragma unroll
  for (int q = 0; q < 10; q++){
    float4 p = hp[q];
    atomicAdd(od + q * 4 + 0, p.x * alpha);
    atomicAdd(od + q * 4 + 1, p.y * alpha);
    atomicAdd(od + q * 4 + 2, p.z * alpha);
    atomicAdd(od + q * 4 + 3, p.w * alpha);
  }
}

// ---------------- final: out = log_softmax(out + b2), wave per row ----------------
__global__ void k_lsm(float* __restrict__ out, const float* __restrict__ b, int N){
  int lane = threadIdx.x & 63;
  int row  = blockIdx.x * 4 + (threadIdx.x >> 6);
  if (row >= N) return;
  float v = (lane < 40) ? out[(size_t)row * 40 + lane] + b[lane] : -INFINITY;
  float mx = v;
  #pragma unroll
  for (int o = 32; o; o >>= 1) mx = fmaxf(mx, __shfl_xor(mx, o, 64));
  float ex = (lane < 40) ? __expf(v - mx) : 0.f;
  float sm = ex;
  #pragma unroll
  for (int o = 32; o; o >>= 1) sm += __shfl_xor(sm, o, 64);
  if (lane < 40) out[(size_t)row * 40 + lane] = v - mx - logf(sm);
}

extern "C" void kernel_launch(void* const* d_in, const int* in_sizes, int n_in,
                              void* d_out, int out_size, void* d_ws, size_t ws_size,
                              hipStream_t stream){
  const float* x   = (const float*)d_in[0];
  const int*   ei  = (const int*)d_in[1];
  const float* W1  = (const float*)d_in[2];
  const float* a1s = (const float*)d_in[3];
  const float* a1d = (const float*)d_in[4];
  const float* b1  = (const float*)d_in[5];
  const float* W2  = (const float*)d_in[6];
  const float* a2s = (const float*)d_in[7];
  const float* a2d = (const float*)d_in[8];
  const float* b2  = (const float*)d_in[9];
  float* out = (float*)d_out;

  const int N = in_sizes[0] / 256;
  const int E = in_sizes[1] / 2;

  float* ws = (float*)d_ws;
  size_t o = 0;
  float*    h1   = ws + o; o += (size_t)N * 64;
  float*    as1  = ws + o; o += (size_t)N * 8;
  float*    ad1  = ws + o; o += (size_t)N * 8;
  unsigned* m1   = (unsigned*)(ws + o); o += (size_t)N * 8;
  float*    den1 = ws + o; o += (size_t)N * 8;
  float*    out1 = ws + o; o += (size_t)N * 64;
  float*    h2   = ws + o; o += (size_t)N * 40;
  float*    as2  = ws + o; o += (size_t)N;
  float*    ad2  = ws + o; o += (size_t)N;
  unsigned* m2   = (unsigned*)(ws + o); o += (size_t)N;
  float*    den2 = ws + o; o += (size_t)N;

  // zero: [m1 | den1 | out1] contiguous, [m2 | den2] contiguous, d_out
  hipMemsetAsync(m1, 0, sizeof(float) * (size_t)N * (8 + 8 + 64), stream);
  hipMemsetAsync(m2, 0, sizeof(float) * (size_t)N * 2, stream);
  hipMemsetAsync(out, 0, sizeof(float) * (size_t)N * 40, stream);

  const int tot = E + N;
  const int tb  = (tot + 255) / 256;

  k_gemm1<<<(N + 15) / 16, 256, 0, stream>>>(x, W1, h1, N);
  k_alpha1<<<((size_t)N * 8 + 255) / 256, 256, 0, stream>>>(h1, a1s, a1d, as1, ad1, N);
  k_emax1<<<tb, 256, 0, stream>>>(ei, E, N, as1, ad1, m1);
  k_esum1<<<tb, 256, 0, stream>>>(ei, E, N, as1, ad1, m1, den1);
  k_escat1<<<tb, 256, 0, stream>>>(ei, E, N, as1, ad1, m1, den1, h1, out1);
  k_bias_relu<<<((size_t)N * 64 + 255) / 256, 256, 0, stream>>>(out1, b1, (size_t)N * 64);
  k_gemm2<<<((size_t)N * 40 + 255) / 256, 256, 0, stream>>>(out1, W2, h2, N);
  k_alpha2<<<(N + 255) / 256, 256, 0, stream>>>(h2, a2s, a2d, as2, ad2, N);
  k_emax2<<<tb, 256, 0, stream>>>(ei, E, N, as2, ad2, m2);
  k_esum2<<<tb, 256, 0, stream>>>(ei, E, N, as2, ad2, m2, den2);
  k_escat2<<<tb, 256, 0, stream>>>(ei, E, N, as2, ad2, m2, den2, h2, out);
  k_lsm<<<(N + 3) / 4, 256, 0, stream>>>(out, b2, N);
}

// Round 2
// 712.660 us; speedup vs baseline: 15.1875x; 15.1875x over previous
//
#include <hip/hip_runtime.h>
#include <math.h>

#define NEG_SLOPE 0.2f
__device__ __forceinline__ float lrelu(float x){ return x >= 0.f ? x : NEG_SLOPE * x; }

__device__ __forceinline__ float wred_max(float v){
  #pragma unroll
  for (int o = 32; o; o >>= 1) v = fmaxf(v, __shfl_xor(v, o, 64));
  return v;
}
__device__ __forceinline__ float wred_sum(float v){
  #pragma unroll
  for (int o = 32; o; o >>= 1) v += __shfl_xor(v, o, 64);
  return v;
}

// ================= CSR build =================
__global__ void k_hist(const int* __restrict__ ei, int E, int N, unsigned* __restrict__ cnt){
  int e = blockIdx.x * blockDim.x + threadIdx.x;
  if (e >= E + N) return;
  int d = (e < E) ? ei[E + e] : (e - E);
  atomicAdd(&cnt[d], 1u);
}

__global__ void k_scan1(const unsigned* __restrict__ cnt, unsigned* __restrict__ scn,
                        unsigned* __restrict__ bsum, int N){
  __shared__ unsigned s[256];
  int t = threadIdx.x; int i = blockIdx.x * 256 + t;
  unsigned v = (i < N) ? cnt[i] : 0u;
  s[t] = v; __syncthreads();
  for (int off = 1; off < 256; off <<= 1){
    unsigned x = (t >= off) ? s[t - off] : 0u; __syncthreads();
    s[t] += x; __syncthreads();
  }
  if (i < N) scn[i] = s[t] - v;            // exclusive within block
  if (t == 255) bsum[blockIdx.x] = s[255]; // block total
}

__global__ void k_scan2(unsigned* __restrict__ bsum, int nb){
  __shared__ unsigned s[512];
  int t = threadIdx.x;
  unsigned v = (t < nb) ? bsum[t] : 0u;
  s[t] = v; __syncthreads();
  for (int off = 1; off < 512; off <<= 1){
    unsigned x = (t >= off) ? s[t - off] : 0u; __syncthreads();
    s[t] += x; __syncthreads();
  }
  if (t < nb) bsum[t] = s[t];              // inclusive
}

__global__ void k_scan3(const unsigned* __restrict__ scn, const unsigned* __restrict__ bsum,
                        unsigned* __restrict__ off_, unsigned* __restrict__ cur, int N){
  int i = blockIdx.x * 256 + threadIdx.x;
  if (i >= N) return;
  unsigned o = scn[i] + (blockIdx.x > 0 ? bsum[blockIdx.x - 1] : 0u);
  off_[i] = o; cur[i] = o;
}

__global__ void k_fill(const int* __restrict__ ei, int E, int N,
                       unsigned* __restrict__ cur, int* __restrict__ srcids){
  int e = blockIdx.x * blockDim.x + threadIdx.x;
  if (e >= E + N) return;
  int s, d;
  if (e < E){ s = ei[e]; d = ei[E + e]; } else { s = e - E; d = s; }
  unsigned p = atomicAdd(&cur[d], 1u);
  srcids[p] = s;
}

// ============ GEMM1 + fused alpha1: h1=x@W1, as1/ad1 dots ============
__global__ __launch_bounds__(256) void k_gemm1(const float* __restrict__ x, const float* __restrict__ W,
                        const float* __restrict__ a1s, const float* __restrict__ a1d,
                        float* __restrict__ h, float* __restrict__ as_, float* __restrict__ ad_, int N){
  int lane = threadIdx.x & 63;
  int wv   = threadIdx.x >> 6;
  int r0   = blockIdx.x * 16 + wv * 4;
  if (r0 >= N) return;
  const float* x0 = x + (size_t)r0 * 256;
  const float* x1 = x + (size_t)min(r0 + 1, N - 1) * 256;
  const float* x2 = x + (size_t)min(r0 + 2, N - 1) * 256;
  const float* x3 = x + (size_t)min(r0 + 3, N - 1) * 256;
  float a0 = 0.f, a1 = 0.f, a2 = 0.f, a3 = 0.f;
  #pragma unroll 8
  for (int k = 0; k < 256; k++){
    float w = W[k * 64 + lane];
    a0 = fmaf(x0[k], w, a0); a1 = fmaf(x1[k], w, a1);
    a2 = fmaf(x2[k], w, a2); a3 = fmaf(x3[k], w, a3);
  }
  float was = a1s[lane], wad = a1d[lane];
  float va[4] = {a0, a1, a2, a3};
  #pragma unroll
  for (int r = 0; r < 4; r++){
    int rr = r0 + r;
    if (rr < N){
      h[(size_t)rr * 64 + lane] = va[r];
      float s = va[r] * was, t = va[r] * wad;
      s += __shfl_xor(s, 1, 64); s += __shfl_xor(s, 2, 64); s += __shfl_xor(s, 4, 64);
      t += __shfl_xor(t, 1, 64); t += __shfl_xor(t, 2, 64); t += __shfl_xor(t, 4, 64);
      if ((lane & 7) == 0){
        as_[(size_t)rr * 8 + (lane >> 3)] = s;
        ad_[(size_t)rr * 8 + (lane >> 3)] = t;
      }
    }
  }
}

// ============ layer-1 per-dst gather: max+sum+accum+bias+relu, no atomics ============
__global__ __launch_bounds__(256) void k_gat1(const unsigned* __restrict__ off_, const unsigned* __restrict__ cur,
    const int* __restrict__ srcids, const float* __restrict__ as_, const float* __restrict__ ad_,
    const float* __restrict__ h1, const float* __restrict__ b1, float* __restrict__ out1, int N){
  int lane = threadIdx.x & 63;
  int wv   = threadIdx.x >> 6;
  int d    = blockIdx.x * 4 + wv;
  if (d >= N) return;
  __shared__ float lds_p[4][64 * 9];
  __shared__ int   lds_s[4][64];
  float* lp = lds_p[wv];
  int*   ls = lds_s[wv];
  unsigned beg = off_[d], fin = cur[d];

  const float4* adp = (const float4*)(ad_ + (size_t)d * 8);
  float4 B0 = adp[0], B1 = adp[1];
  float ad[8] = {B0.x, B0.y, B0.z, B0.w, B1.x, B1.y, B1.z, B1.w};

  // pass A: per-head max
  float pm[8];
  #pragma unroll
  for (int h = 0; h < 8; h++) pm[h] = -INFINITY;
  for (unsigned i = beg + lane; i < fin; i += 64){
    int s = srcids[i];
    const float4* ap = (const float4*)(as_ + (size_t)s * 8);
    float4 A0 = ap[0], A1 = ap[1];
    float ev[8] = {A0.x, A0.y, A0.z, A0.w, A1.x, A1.y, A1.z, A1.w};
    #pragma unroll
    for (int h = 0; h < 8; h++) pm[h] = fmaxf(pm[h], lrelu(ev[h] + ad[h]));
  }
  #pragma unroll
  for (int h = 0; h < 8; h++) pm[h] = wred_max(pm[h]);

  // pass B+C: exp-sum + weighted accumulation (lane = output channel)
  float ps[8] = {0.f,0.f,0.f,0.f,0.f,0.f,0.f,0.f};
  float acc = 0.f;
  int hh = lane >> 3;
  for (unsigned base = beg; base < fin; base += 64){
    unsigned i = base + lane;
    int nthis = (int)min(64u, fin - base);
    if (i < fin){
      int s = srcids[i];
      ls[lane] = s;
      const float4* ap = (const float4*)(as_ + (size_t)s * 8);
      float4 A0 = ap[0], A1 = ap[1];
      float ev[8] = {A0.x, A0.y, A0.z, A0.w, A1.x, A1.y, A1.z, A1.w};
      #pragma unroll
      for (int h = 0; h < 8; h++){
        float p = __expf(lrelu(ev[h] + ad[h]) - pm[h]);
        ps[h] += p;
        lp[lane * 9 + h] = p;
      }
    }
    asm volatile("s_waitcnt lgkmcnt(0)" ::: "memory");
    __builtin_amdgcn_sched_barrier(0);
    for (int e = 0; e < nthis; e++){
      float pv = lp[e * 9 + hh];
      int se = ls[e];
      acc = fmaf(pv, h1[(size_t)se * 64 + lane], acc);
    }
    asm volatile("" ::: "memory");
  }
  #pragma unroll
  for (int h = 0; h < 8; h++) ps[h] = wred_sum(ps[h]);
  // select this lane's head denominator (static unrolled select chain)
  float den = ps[0];
  #pragma unroll
  for (int h = 1; h < 8; h++) den = (hh == h) ? ps[h] : den;
  float v = acc / den + b1[lane];
  out1[(size_t)d * 64 + lane] = v > 0.f ? v : 0.f;
}

// ============ GEMM2: h2 = out1 @ W2 ============
__global__ void k_gemm2(const float* __restrict__ in, const float* __restrict__ W,
                        float* __restrict__ h2, int N){
  int i = blockIdx.x * blockDim.x + threadIdx.x;
  if (i >= N * 40) return;
  int c = i % 40, n = i / 40;
  const float* r = in + (size_t)n * 64;
  float acc = 0.f;
  #pragma unroll 8
  for (int k = 0; k < 64; k++) acc = fmaf(r[k], W[k * 40 + c], acc);
  h2[i] = acc;
}

__global__ void k_alpha2(const float* __restrict__ h2, const float* __restrict__ asrc,
                         const float* __restrict__ adst, float* __restrict__ as_,
                         float* __restrict__ ad_, int N){
  int n = blockIdx.x * blockDim.x + threadIdx.x;
  if (n >= N) return;
  const float* r = h2 + (size_t)n * 40;
  float s = 0.f, d = 0.f;
  #pragma unroll 8
  for (int c = 0; c < 40; c++){
    float v = r[c];
    s = fmaf(v, asrc[c], s);
    d = fmaf(v, adst[c], d);
  }
  as_[n] = s; ad_[n] = d;
}

// ============ layer-2 per-dst gather (H=1, C=40) ============
__global__ __launch_bounds__(256) void k_gat2(const unsigned* __restrict__ off_, const unsigned* __restrict__ cur,
    const int* __restrict__ srcids, const float* __restrict__ as_, const float* __restrict__ ad_,
    const float* __restrict__ h2, float* __restrict__ out, int N){
  int lane = threadIdx.x & 63;
  int wv   = threadIdx.x >> 6;
  int d    = blockIdx.x * 4 + wv;
  if (d >= N) return;
  __shared__ float lds_p[4][64];
  __shared__ int   lds_s[4][64];
  float* lp = lds_p[wv];
  int*   ls = lds_s[wv];
  unsigned beg = off_[d], fin = cur[d];
  float add = ad_[d];

  float pm = -INFINITY;
  for (unsigned i = beg + lane; i < fin; i += 64)
    pm = fmaxf(pm, lrelu(as_[srcids[i]] + add));
  pm = wred_max(pm);

  float ps = 0.f, acc = 0.f;
  for (unsigned base = beg; base < fin; base += 64){
    unsigned i = base + lane;
    int nthis = (int)min(64u, fin - base);
    if (i < fin){
      int s = srcids[i];
      float p = __expf(lrelu(as_[s] + add) - pm);
      ps += p; ls[lane] = s; lp[lane] = p;
    }
    asm volatile("s_waitcnt lgkmcnt(0)" ::: "memory");
    __builtin_amdgcn_sched_barrier(0);
    if (lane < 40){
      for (int e = 0; e < nthis; e++)
        acc = fmaf(lp[e], h2[(size_t)ls[e] * 40 + lane], acc);
    }
    asm volatile("" ::: "memory");
  }
  ps = wred_sum(ps);
  if (lane < 40) out[(size_t)d * 40 + lane] = acc / ps;
}

// ============ final: out = log_softmax(out + b2) ============
__global__ void k_lsm(float* __restrict__ out, const float* __restrict__ b, int N){
  int lane = threadIdx.x & 63;
  int row  = blockIdx.x * 4 + (threadIdx.x >> 6);
  if (row >= N) return;
  float v = (lane < 40) ? out[(size_t)row * 40 + lane] + b[lane] : -INFINITY;
  float mx = v;
  #pragma unroll
  for (int o = 32; o; o >>= 1) mx = fmaxf(mx, __shfl_xor(mx, o, 64));
  float ex = (lane < 40) ? __expf(v - mx) : 0.f;
  float sm = ex;
  #pragma unroll
  for (int o = 32; o; o >>= 1) sm += __shfl_xor(sm, o, 64);
  if (lane < 40) out[(size_t)row * 40 + lane] = v - mx - logf(sm);
}

extern "C" void kernel_launch(void* const* d_in, const int* in_sizes, int n_in,
                              void* d_out, int out_size, void* d_ws, size_t ws_size,
                              hipStream_t stream){
  const float* x   = (const float*)d_in[0];
  const int*   ei  = (const int*)d_in[1];
  const float* W1  = (const float*)d_in[2];
  const float* a1s = (const float*)d_in[3];
  const float* a1d = (const float*)d_in[4];
  const float* b1  = (const float*)d_in[5];
  const float* W2  = (const float*)d_in[6];
  const float* a2s = (const float*)d_in[7];
  const float* a2d = (const float*)d_in[8];
  const float* b2  = (const float*)d_in[9];
  float* out = (float*)d_out;

  const int N = in_sizes[0] / 256;
  const int E = in_sizes[1] / 2;

  float* ws = (float*)d_ws;
  size_t o = 0;
  float* h1   = ws + o; o += (size_t)N * 64;
  float* as1  = ws + o; o += (size_t)N * 8;
  float* ad1  = ws + o; o += (size_t)N * 8;
  float* out1 = ws + o; o += (size_t)N * 64;   // hosts scn during CSR build
  float* h2   = ws + o; o += (size_t)N * 40;   // hosts bsum during CSR build
  unsigned* cnt  = (unsigned*)(ws + o); o += (size_t)N;   // becomes cur after scan
  unsigned* off_ = (unsigned*)(ws + o); o += (size_t)N;
  int* srcids    = (int*)(ws + o);      o += (size_t)(E + N);
  unsigned* scn  = (unsigned*)out1;
  unsigned* bsum = (unsigned*)h2;
  float* as2 = as1;   // layer-1 alphas dead by then
  float* ad2 = ad1;

  const int tot = E + N;
  const int tb  = (tot + 255) / 256;
  const int nb1 = (N + 255) / 256;   // 391 <= 512

  hipMemsetAsync(cnt, 0, sizeof(unsigned) * (size_t)N, stream);

  // CSR build (amortized over both layers)
  k_hist <<<tb, 256, 0, stream>>>(ei, E, N, cnt);
  k_scan1<<<nb1, 256, 0, stream>>>(cnt, scn, bsum, N);
  k_scan2<<<1, 512, 0, stream>>>(bsum, nb1);
  k_scan3<<<nb1, 256, 0, stream>>>(scn, bsum, off_, cnt, N);   // cnt becomes cursor
  k_fill <<<tb, 256, 0, stream>>>(ei, E, N, cnt, srcids);      // cnt ends as segment-end

  // layer 1
  k_gemm1<<<(N + 15) / 16, 256, 0, stream>>>(x, W1, a1s, a1d, h1, as1, ad1, N);
  k_gat1 <<<(N + 3) / 4, 256, 0, stream>>>(off_, cnt, srcids, as1, ad1, h1, b1, out1, N);

  // layer 2
  k_gemm2 <<<((size_t)N * 40 + 255) / 256, 256, 0, stream>>>(out1, W2, h2, N);
  k_alpha2<<<(N + 255) / 256, 256, 0, stream>>>(h2, a2s, a2d, as2, ad2, N);
  k_gat2  <<<(N + 3) / 4, 256, 0, stream>>>(off_, cnt, srcids, as2, ad2, h2, out, N);
  k_lsm   <<<(N + 3) / 4, 256, 0, stream>>>(out, b2, N);
}

// Round 3
// 568.330 us; speedup vs baseline: 19.0444x; 1.2540x over previous
//
#include <hip/hip_runtime.h>
#include <math.h>

#define NEG_SLOPE 0.2f
__device__ __forceinline__ float lrelu(float x){ return x >= 0.f ? x : NEG_SLOPE * x; }

typedef __attribute__((ext_vector_type(8))) short bf16x8;
typedef __attribute__((ext_vector_type(4))) float f32x4;

__device__ __forceinline__ float wred_max(float v){
  #pragma unroll
  for (int o = 32; o; o >>= 1) v = fmaxf(v, __shfl_xor(v, o, 64));
  return v;
}
__device__ __forceinline__ float wred_sum(float v){
  #pragma unroll
  for (int o = 32; o; o >>= 1) v += __shfl_xor(v, o, 64);
  return v;
}

// truncate fp32 -> bf16 (bits), and bits -> fp32
__device__ __forceinline__ float bfhi_f(float f){
  return __uint_as_float(__float_as_uint(f) & 0xFFFF0000u);
}

// ================= CSR build =================
__global__ void k_hist(const int* __restrict__ ei, int E, int N, unsigned* __restrict__ cnt){
  int e = blockIdx.x * blockDim.x + threadIdx.x;
  if (e >= E + N) return;
  int d = (e < E) ? ei[E + e] : (e - E);
  atomicAdd(&cnt[d], 1u);
}

__global__ void k_scan1(const unsigned* __restrict__ cnt, unsigned* __restrict__ scn,
                        unsigned* __restrict__ bsum, int N){
  __shared__ unsigned s[256];
  int t = threadIdx.x; int i = blockIdx.x * 256 + t;
  unsigned v = (i < N) ? cnt[i] : 0u;
  s[t] = v; __syncthreads();
  for (int off = 1; off < 256; off <<= 1){
    unsigned x = (t >= off) ? s[t - off] : 0u; __syncthreads();
    s[t] += x; __syncthreads();
  }
  if (i < N) scn[i] = s[t] - v;
  if (t == 255) bsum[blockIdx.x] = s[255];
}

__global__ void k_scan2(unsigned* __restrict__ bsum, int nb){
  __shared__ unsigned s[512];
  int t = threadIdx.x;
  unsigned v = (t < nb) ? bsum[t] : 0u;
  s[t] = v; __syncthreads();
  for (int off = 1; off < 512; off <<= 1){
    unsigned x = (t >= off) ? s[t - off] : 0u; __syncthreads();
    s[t] += x; __syncthreads();
  }
  if (t < nb) bsum[t] = s[t];
}

__global__ void k_scan3(const unsigned* __restrict__ scn, const unsigned* __restrict__ bsum,
                        unsigned* __restrict__ off_, unsigned* __restrict__ cur, int N){
  int i = blockIdx.x * 256 + threadIdx.x;
  if (i >= N) return;
  unsigned o = scn[i] + (blockIdx.x > 0 ? bsum[blockIdx.x - 1] : 0u);
  off_[i] = o; cur[i] = o;
}

__global__ void k_fill(const int* __restrict__ ei, int E, int N,
                       unsigned* __restrict__ cur, int* __restrict__ srcids){
  int e = blockIdx.x * blockDim.x + threadIdx.x;
  if (e >= E + N) return;
  int s, d;
  if (e < E){ s = ei[e]; d = ei[E + e]; } else { s = e - E; d = s; }
  unsigned p = atomicAdd(&cur[d], 1u);
  srcids[p] = s;
}

// ============ W prep: Wt_hi/Wt_lo[64][256] bf16 = transpose+split of W[256][64] ============
__global__ void k_wprep(const float* __restrict__ W, short* __restrict__ wt_hi,
                        short* __restrict__ wt_lo){
  int i = blockIdx.x * 256 + threadIdx.x;    // 16384
  int k = i >> 6, c = i & 63;
  float v = W[i];                             // W[k][c]
  unsigned u = __float_as_uint(v);
  short hi = (short)(u >> 16);
  float lo = v - bfhi_f(v);
  wt_hi[c * 256 + k] = hi;
  wt_lo[c * 256 + k] = (short)(__float_as_uint(lo) >> 16);
}

// ============ GEMM1 via MFMA bf16 hi/lo split: h1 = x @ W1 ============
__global__ __launch_bounds__(256) void k_gemm1_mfma(const float* __restrict__ x,
    const short* __restrict__ wt_hi, const short* __restrict__ wt_lo,
    float* __restrict__ h, int N){
  int lane = threadIdx.x & 63;
  int wv   = threadIdx.x >> 6;
  int r0   = blockIdx.x * 64 + wv * 16;
  if (r0 >= N) return;
  int row  = r0 + (lane & 15);
  int kg   = lane >> 4;                      // 0..3
  const float* xr = x + (size_t)min(row, N - 1) * 256 + kg * 8;

  f32x4 acc[4];
  #pragma unroll
  for (int ct = 0; ct < 4; ct++) acc[ct] = (f32x4){0.f, 0.f, 0.f, 0.f};

  #pragma unroll 2
  for (int kt = 0; kt < 8; kt++){
    float4 v0 = *(const float4*)(xr + kt * 32);
    float4 v1 = *(const float4*)(xr + kt * 32 + 4);
    unsigned u[8] = {__float_as_uint(v0.x), __float_as_uint(v0.y), __float_as_uint(v0.z), __float_as_uint(v0.w),
                     __float_as_uint(v1.x), __float_as_uint(v1.y), __float_as_uint(v1.z), __float_as_uint(v1.w)};
    union { bf16x8 v; unsigned u[4]; } ahi, alo;
    #pragma unroll
    for (int j = 0; j < 4; j++)
      ahi.u[j] = __builtin_amdgcn_perm(u[2*j+1], u[2*j], 0x07060302);
    float lo[8];
    lo[0] = v0.x - bfhi_f(v0.x); lo[1] = v0.y - bfhi_f(v0.y);
    lo[2] = v0.z - bfhi_f(v0.z); lo[3] = v0.w - bfhi_f(v0.w);
    lo[4] = v1.x - bfhi_f(v1.x); lo[5] = v1.y - bfhi_f(v1.y);
    lo[6] = v1.z - bfhi_f(v1.z); lo[7] = v1.w - bfhi_f(v1.w);
    #pragma unroll
    for (int j = 0; j < 4; j++)
      alo.u[j] = __builtin_amdgcn_perm(__float_as_uint(lo[2*j+1]), __float_as_uint(lo[2*j]), 0x07060302);

    #pragma unroll
    for (int ct = 0; ct < 4; ct++){
      int wcol = ct * 16 + (lane & 15);
      const bf16x8 bhi = *(const bf16x8*)(wt_hi + wcol * 256 + kt * 32 + kg * 8);
      const bf16x8 blo = *(const bf16x8*)(wt_lo + wcol * 256 + kt * 32 + kg * 8);
      acc[ct] = __builtin_amdgcn_mfma_f32_16x16x32_bf16(ahi.v, bhi, acc[ct], 0, 0, 0);
      acc[ct] = __builtin_amdgcn_mfma_f32_16x16x32_bf16(ahi.v, blo, acc[ct], 0, 0, 0);
      acc[ct] = __builtin_amdgcn_mfma_f32_16x16x32_bf16(alo.v, bhi, acc[ct], 0, 0, 0);
    }
  }
  // D: col = ct*16 + (lane&15), row = r0 + (lane>>4)*4 + r
  #pragma unroll
  for (int ct = 0; ct < 4; ct++){
    #pragma unroll
    for (int r = 0; r < 4; r++){
      int rr = r0 + (lane >> 4) * 4 + r;
      if (rr < N) h[(size_t)rr * 64 + ct * 16 + (lane & 15)] = acc[ct][r];
    }
  }
}

// ============ alpha1: per (node, head) dot over C=8 ============
__global__ void k_alpha1(const float* __restrict__ h, const float* __restrict__ asrc,
                         const float* __restrict__ adst, float* __restrict__ as_,
                         float* __restrict__ ad_, int N){
  int i = blockIdx.x * blockDim.x + threadIdx.x;
  if (i >= N * 8) return;
  int hd = i & 7;
  const float* hp = h + (size_t)(i >> 3) * 64 + hd * 8;
  float s = 0.f, d = 0.f;
  #pragma unroll
  for (int c = 0; c < 8; c++){
    float v = hp[c];
    s = fmaf(v, asrc[hd * 8 + c], s);
    d = fmaf(v, adst[hd * 8 + c], d);
  }
  as_[i] = s; ad_[i] = d;
}

// ============ layer-1 per-dst gather: max+sum+accum+bias+relu, no atomics ============
__global__ __launch_bounds__(256) void k_gat1(const unsigned* __restrict__ off_, const unsigned* __restrict__ cur,
    const int* __restrict__ srcids, const float* __restrict__ as_, const float* __restrict__ ad_,
    const float* __restrict__ h1, const float* __restrict__ b1, float* __restrict__ out1, int N){
  int lane = threadIdx.x & 63;
  int wv   = threadIdx.x >> 6;
  int d    = blockIdx.x * 4 + wv;
  if (d >= N) return;
  __shared__ float lds_p[4][64 * 9];
  __shared__ int   lds_s[4][64];
  float* lp = lds_p[wv];
  int*   ls = lds_s[wv];
  unsigned beg = off_[d], fin = cur[d];

  const float4* adp = (const float4*)(ad_ + (size_t)d * 8);
  float4 B0 = adp[0], B1 = adp[1];
  float ad[8] = {B0.x, B0.y, B0.z, B0.w, B1.x, B1.y, B1.z, B1.w};

  float pm[8];
  #pragma unroll
  for (int h = 0; h < 8; h++) pm[h] = -INFINITY;
  for (unsigned i = beg + lane; i < fin; i += 64){
    int s = srcids[i];
    const float4* ap = (const float4*)(as_ + (size_t)s * 8);
    float4 A0 = ap[0], A1 = ap[1];
    float ev[8] = {A0.x, A0.y, A0.z, A0.w, A1.x, A1.y, A1.z, A1.w};
    #pragma unroll
    for (int h = 0; h < 8; h++) pm[h] = fmaxf(pm[h], lrelu(ev[h] + ad[h]));
  }
  #pragma unroll
  for (int h = 0; h < 8; h++) pm[h] = wred_max(pm[h]);

  float ps[8] = {0.f,0.f,0.f,0.f,0.f,0.f,0.f,0.f};
  float acc = 0.f;
  int hh = lane >> 3;
  for (unsigned base = beg; base < fin; base += 64){
    unsigned i = base + lane;
    int nthis = (int)min(64u, fin - base);
    if (i < fin){
      int s = srcids[i];
      ls[lane] = s;
      const float4* ap = (const float4*)(as_ + (size_t)s * 8);
      float4 A0 = ap[0], A1 = ap[1];
      float ev[8] = {A0.x, A0.y, A0.z, A0.w, A1.x, A1.y, A1.z, A1.w};
      #pragma unroll
      for (int h = 0; h < 8; h++){
        float p = __expf(lrelu(ev[h] + ad[h]) - pm[h]);
        ps[h] += p;
        lp[lane * 9 + h] = p;
      }
    }
    asm volatile("s_waitcnt lgkmcnt(0)" ::: "memory");
    __builtin_amdgcn_sched_barrier(0);
    for (int e = 0; e < nthis; e++){
      float pv = lp[e * 9 + hh];
      int se = ls[e];
      acc = fmaf(pv, h1[(size_t)se * 64 + lane], acc);
    }
    asm volatile("" ::: "memory");
  }
  #pragma unroll
  for (int h = 0; h < 8; h++) ps[h] = wred_sum(ps[h]);
  float den = ps[0];
  #pragma unroll
  for (int h = 1; h < 8; h++) den = (hh == h) ? ps[h] : den;
  float v = acc / den + b1[lane];
  out1[(size_t)d * 64 + lane] = v > 0.f ? v : 0.f;
}

// ============ GEMM2: h2 = out1 @ W2 ============
__global__ void k_gemm2(const float* __restrict__ in, const float* __restrict__ W,
                        float* __restrict__ h2, int N){
  int i = blockIdx.x * blockDim.x + threadIdx.x;
  if (i >= N * 40) return;
  int c = i % 40, n = i / 40;
  const float* r = in + (size_t)n * 64;
  float acc = 0.f;
  #pragma unroll 8
  for (int k = 0; k < 64; k++) acc = fmaf(r[k], W[k * 40 + c], acc);
  h2[i] = acc;
}

__global__ void k_alpha2(const float* __restrict__ h2, const float* __restrict__ asrc,
                         const float* __restrict__ adst, float* __restrict__ as_,
                         float* __restrict__ ad_, int N){
  int n = blockIdx.x * blockDim.x + threadIdx.x;
  if (n >= N) return;
  const float* r = h2 + (size_t)n * 40;
  float s = 0.f, d = 0.f;
  #pragma unroll 8
  for (int c = 0; c < 40; c++){
    float v = r[c];
    s = fmaf(v, asrc[c], s);
    d = fmaf(v, adst[c], d);
  }
  as_[n] = s; ad_[n] = d;
}

// ============ layer-2 per-dst gather (H=1, C=40) ============
__global__ __launch_bounds__(256) void k_gat2(const unsigned* __restrict__ off_, const unsigned* __restrict__ cur,
    const int* __restrict__ srcids, const float* __restrict__ as_, const float* __restrict__ ad_,
    const float* __restrict__ h2, float* __restrict__ out, int N){
  int lane = threadIdx.x & 63;
  int wv   = threadIdx.x >> 6;
  int d    = blockIdx.x * 4 + wv;
  if (d >= N) return;
  __shared__ float lds_p[4][64];
  __shared__ int   lds_s[4][64];
  float* lp = lds_p[wv];
  int*   ls = lds_s[wv];
  unsigned beg = off_[d], fin = cur[d];
  float add = ad_[d];

  float pm = -INFINITY;
  for (unsigned i = beg + lane; i < fin; i += 64)
    pm = fmaxf(pm, lrelu(as_[srcids[i]] + add));
  pm = wred_max(pm);

  float ps = 0.f, acc = 0.f;
  for (unsigned base = beg; base < fin; base += 64){
    unsigned i = base + lane;
    int nthis = (int)min(64u, fin - base);
    if (i < fin){
      int s = srcids[i];
      float p = __expf(lrelu(as_[s] + add) - pm);
      ps += p; ls[lane] = s; lp[lane] = p;
    }
    asm volatile("s_waitcnt lgkmcnt(0)" ::: "memory");
    __builtin_amdgcn_sched_barrier(0);
    if (lane < 40){
      for (int e = 0; e < nthis; e++)
        acc = fmaf(lp[e], h2[(size_t)ls[e] * 40 + lane], acc);
    }
    asm volatile("" ::: "memory");
  }
  ps = wred_sum(ps);
  if (lane < 40) out[(size_t)d * 40 + lane] = acc / ps;
}

// ============ final: out = log_softmax(out + b2) ============
__global__ void k_lsm(float* __restrict__ out, const float* __restrict__ b, int N){
  int lane = threadIdx.x & 63;
  int row  = blockIdx.x * 4 + (threadIdx.x >> 6);
  if (row >= N) return;
  float v = (lane < 40) ? out[(size_t)row * 40 + lane] + b[lane] : -INFINITY;
  float mx = v;
  #pragma unroll
  for (int o = 32; o; o >>= 1) mx = fmaxf(mx, __shfl_xor(mx, o, 64));
  float ex = (lane < 40) ? __expf(v - mx) : 0.f;
  float sm = ex;
  #pragma unroll
  for (int o = 32; o; o >>= 1) sm += __shfl_xor(sm, o, 64);
  if (lane < 40) out[(size_t)row * 40 + lane] = v - mx - logf(sm);
}

extern "C" void kernel_launch(void* const* d_in, const int* in_sizes, int n_in,
                              void* d_out, int out_size, void* d_ws, size_t ws_size,
                              hipStream_t stream){
  const float* x   = (const float*)d_in[0];
  const int*   ei  = (const int*)d_in[1];
  const float* W1  = (const float*)d_in[2];
  const float* a1s = (const float*)d_in[3];
  const float* a1d = (const float*)d_in[4];
  const float* b1  = (const float*)d_in[5];
  const float* W2  = (const float*)d_in[6];
  const float* a2s = (const float*)d_in[7];
  const float* a2d = (const float*)d_in[8];
  const float* b2  = (const float*)d_in[9];
  float* out = (float*)d_out;

  const int N = in_sizes[0] / 256;
  const int E = in_sizes[1] / 2;

  float* ws = (float*)d_ws;
  size_t o = 0;
  float* h1   = ws + o; o += (size_t)N * 64;
  float* as1  = ws + o; o += (size_t)N * 8;
  float* ad1  = ws + o; o += (size_t)N * 8;
  float* out1 = ws + o; o += (size_t)N * 64;   // hosts scn during CSR build
  float* h2   = ws + o; o += (size_t)N * 40;   // hosts bsum during CSR build
  unsigned* cnt  = (unsigned*)(ws + o); o += (size_t)N;
  unsigned* off_ = (unsigned*)(ws + o); o += (size_t)N;
  int* srcids    = (int*)(ws + o);      o += (size_t)(E + N);
  short* wt_hi   = (short*)(ws + o);    o += 8192;   // 16384 bf16
  short* wt_lo   = (short*)(ws + o);    o += 8192;
  unsigned* scn  = (unsigned*)out1;
  unsigned* bsum = (unsigned*)h2;
  float* as2 = as1;
  float* ad2 = ad1;

  const int tot = E + N;
  const int tb  = (tot + 255) / 256;
  const int nb1 = (N + 255) / 256;

  hipMemsetAsync(cnt, 0, sizeof(unsigned) * (size_t)N, stream);

  // CSR build
  k_hist <<<tb, 256, 0, stream>>>(ei, E, N, cnt);
  k_scan1<<<nb1, 256, 0, stream>>>(cnt, scn, bsum, N);
  k_scan2<<<1, 512, 0, stream>>>(bsum, nb1);
  k_scan3<<<nb1, 256, 0, stream>>>(scn, bsum, off_, cnt, N);
  k_fill <<<tb, 256, 0, stream>>>(ei, E, N, cnt, srcids);

  // layer 1
  k_wprep<<<64, 256, 0, stream>>>(W1, wt_hi, wt_lo);
  k_gemm1_mfma<<<(N + 63) / 64, 256, 0, stream>>>(x, wt_hi, wt_lo, h1, N);
  k_alpha1<<<((size_t)N * 8 + 255) / 256, 256, 0, stream>>>(h1, a1s, a1d, as1, ad1, N);
  k_gat1 <<<(N + 3) / 4, 256, 0, stream>>>(off_, cnt, srcids, as1, ad1, h1, b1, out1, N);

  // layer 2
  k_gemm2 <<<((size_t)N * 40 + 255) / 256, 256, 0, stream>>>(out1, W2, h2, N);
  k_alpha2<<<(N + 255) / 256, 256, 0, stream>>>(h2, a2s, a2d, as2, ad2, N);
  k_gat2  <<<(N + 3) / 4, 256, 0, stream>>>(off_, cnt, srcids, as2, ad2, h2, out, N);
  k_lsm   <<<(N + 3) / 4, 256, 0, stream>>>(out, b2, N);
}

// Round 4
// 531.173 us; speedup vs baseline: 20.3766x; 1.0700x over previous
//
#include <hip/hip_runtime.h>
#include <math.h>

#define NEG_SLOPE 0.2f
__device__ __forceinline__ float lrelu(float x){ return x >= 0.f ? x : NEG_SLOPE * x; }

typedef __attribute__((ext_vector_type(8))) short bf16x8;
typedef __attribute__((ext_vector_type(4))) float f32x4;

__device__ __forceinline__ float wred_sum(float v){
  #pragma unroll
  for (int o = 32; o; o >>= 1) v += __shfl_xor(v, o, 64);
  return v;
}

__device__ __forceinline__ float bfhi_f(float f){
  return __uint_as_float(__float_as_uint(f) & 0xFFFF0000u);
}
// fp32 -> bf16 RTNE
__device__ __forceinline__ unsigned short f2bf(float f){
  unsigned u = __float_as_uint(f);
  unsigned r = u + 0x7FFFu + ((u >> 16) & 1u);
  return (unsigned short)(r >> 16);
}

// ================= CSR build =================
__global__ void k_hist(const int* __restrict__ ei, int E, int N, unsigned* __restrict__ cnt){
  int e = blockIdx.x * blockDim.x + threadIdx.x;
  if (e >= E + N) return;
  int d = (e < E) ? ei[E + e] : (e - E);
  atomicAdd(&cnt[d], 1u);
}

__global__ void k_scan1(const unsigned* __restrict__ cnt, unsigned* __restrict__ scn,
                        unsigned* __restrict__ bsum, int N){
  __shared__ unsigned s[256];
  int t = threadIdx.x; int i = blockIdx.x * 256 + t;
  unsigned v = (i < N) ? cnt[i] : 0u;
  s[t] = v; __syncthreads();
  for (int off = 1; off < 256; off <<= 1){
    unsigned x = (t >= off) ? s[t - off] : 0u; __syncthreads();
    s[t] += x; __syncthreads();
  }
  if (i < N) scn[i] = s[t] - v;
  if (t == 255) bsum[blockIdx.x] = s[255];
}

__global__ void k_scan2(unsigned* __restrict__ bsum, int nb){
  __shared__ unsigned s[512];
  int t = threadIdx.x;
  unsigned v = (t < nb) ? bsum[t] : 0u;
  s[t] = v; __syncthreads();
  for (int off = 1; off < 512; off <<= 1){
    unsigned x = (t >= off) ? s[t - off] : 0u; __syncthreads();
    s[t] += x; __syncthreads();
  }
  if (t < nb) bsum[t] = s[t];
}

__global__ void k_scan3(const unsigned* __restrict__ scn, const unsigned* __restrict__ bsum,
                        unsigned* __restrict__ off_, unsigned* __restrict__ cur, int N){
  int i = blockIdx.x * 256 + threadIdx.x;
  if (i >= N) return;
  unsigned o = scn[i] + (blockIdx.x > 0 ? bsum[blockIdx.x - 1] : 0u);
  off_[i] = o; cur[i] = o;
}

__global__ void k_fill(const int* __restrict__ ei, int E, int N,
                       unsigned* __restrict__ cur, int* __restrict__ srcids){
  int e = blockIdx.x * blockDim.x + threadIdx.x;
  if (e >= E + N) return;
  int s, d;
  if (e < E){ s = ei[e]; d = ei[E + e]; } else { s = e - E; d = s; }
  unsigned p = atomicAdd(&cur[d], 1u);
  srcids[p] = s;
}

// ============ W prep: Wt_hi/Wt_lo[64][256] bf16 = transpose+split of W[256][64] ============
__global__ void k_wprep(const float* __restrict__ W, short* __restrict__ wt_hi,
                        short* __restrict__ wt_lo){
  int i = blockIdx.x * 256 + threadIdx.x;    // 16384
  int k = i >> 6, c = i & 63;
  float v = W[i];
  unsigned u = __float_as_uint(v);
  short hi = (short)(u >> 16);
  float lo = v - bfhi_f(v);
  wt_hi[c * 256 + k] = hi;
  wt_lo[c * 256 + k] = (short)(__float_as_uint(lo) >> 16);
}

// ============ GEMM1 via MFMA (hi/lo split) + fused alpha1 + bf16 h1 write ============
__global__ __launch_bounds__(256) void k_gemm1_mfma(const float* __restrict__ x,
    const short* __restrict__ wt_hi, const short* __restrict__ wt_lo,
    const float* __restrict__ a1s, const float* __restrict__ a1d,
    unsigned short* __restrict__ h1b, float* __restrict__ as_, float* __restrict__ ad_, int N){
  int lane = threadIdx.x & 63;
  int wv   = threadIdx.x >> 6;
  int r0   = blockIdx.x * 64 + wv * 16;
  if (r0 >= N) return;
  int col16 = lane & 15;
  int kg    = lane >> 4;                     // A k-group; also D row-group
  const float* xr = x + (size_t)min(r0 + col16, N - 1) * 256 + kg * 8;

  f32x4 acc[4];
  #pragma unroll
  for (int ct = 0; ct < 4; ct++) acc[ct] = (f32x4){0.f, 0.f, 0.f, 0.f};

  #pragma unroll 2
  for (int kt = 0; kt < 8; kt++){
    float4 v0 = *(const float4*)(xr + kt * 32);
    float4 v1 = *(const float4*)(xr + kt * 32 + 4);
    unsigned u[8] = {__float_as_uint(v0.x), __float_as_uint(v0.y), __float_as_uint(v0.z), __float_as_uint(v0.w),
                     __float_as_uint(v1.x), __float_as_uint(v1.y), __float_as_uint(v1.z), __float_as_uint(v1.w)};
    union { bf16x8 v; unsigned u[4]; } ahi, alo;
    #pragma unroll
    for (int j = 0; j < 4; j++)
      ahi.u[j] = __builtin_amdgcn_perm(u[2*j+1], u[2*j], 0x07060302);
    float lo[8];
    lo[0] = v0.x - bfhi_f(v0.x); lo[1] = v0.y - bfhi_f(v0.y);
    lo[2] = v0.z - bfhi_f(v0.z); lo[3] = v0.w - bfhi_f(v0.w);
    lo[4] = v1.x - bfhi_f(v1.x); lo[5] = v1.y - bfhi_f(v1.y);
    lo[6] = v1.z - bfhi_f(v1.z); lo[7] = v1.w - bfhi_f(v1.w);
    #pragma unroll
    for (int j = 0; j < 4; j++)
      alo.u[j] = __builtin_amdgcn_perm(__float_as_uint(lo[2*j+1]), __float_as_uint(lo[2*j]), 0x07060302);

    #pragma unroll
    for (int ct = 0; ct < 4; ct++){
      int wcol = ct * 16 + col16;
      const bf16x8 bhi = *(const bf16x8*)(wt_hi + wcol * 256 + kt * 32 + kg * 8);
      const bf16x8 blo = *(const bf16x8*)(wt_lo + wcol * 256 + kt * 32 + kg * 8);
      acc[ct] = __builtin_amdgcn_mfma_f32_16x16x32_bf16(ahi.v, bhi, acc[ct], 0, 0, 0);
      acc[ct] = __builtin_amdgcn_mfma_f32_16x16x32_bf16(ahi.v, blo, acc[ct], 0, 0, 0);
      acc[ct] = __builtin_amdgcn_mfma_f32_16x16x32_bf16(alo.v, bhi, acc[ct], 0, 0, 0);
    }
  }

  // epilogue: bf16 h1 write + per-head alpha dots
  float cs[4], cd[4];
  #pragma unroll
  for (int ct = 0; ct < 4; ct++){ cs[ct] = a1s[ct * 16 + col16]; cd[ct] = a1d[ct * 16 + col16]; }
  #pragma unroll
  for (int r = 0; r < 4; r++){
    int rr = r0 + kg * 4 + r;                // D row
    bool ok = rr < N;
    #pragma unroll
    for (int ct = 0; ct < 4; ct++){
      float v = acc[ct][r];
      if (ok) h1b[(size_t)rr * 64 + ct * 16 + col16] = f2bf(v);
      float s = v * cs[ct];
      float t = v * cd[ct];
      s += __shfl_xor(s, 1, 64); s += __shfl_xor(s, 2, 64); s += __shfl_xor(s, 4, 64);
      t += __shfl_xor(t, 1, 64); t += __shfl_xor(t, 2, 64); t += __shfl_xor(t, 4, 64);
      if (ok && (col16 & 7) == 0){
        int head = ct * 2 + (col16 >> 3);
        as_[(size_t)rr * 8 + head] = s;
        ad_[(size_t)rr * 8 + head] = t;
      }
    }
  }
}

// ============ layer-1 per-dst gather: single pass, no max, bf16 messages ============
__global__ __launch_bounds__(256) void k_gat1(const unsigned* __restrict__ off_, const unsigned* __restrict__ cur,
    const int* __restrict__ srcids, const float* __restrict__ as_, const float* __restrict__ ad_,
    const unsigned short* __restrict__ h1b, const float* __restrict__ b1, float* __restrict__ out1, int N){
  int lane = threadIdx.x & 63;
  int wv   = threadIdx.x >> 6;
  int d    = blockIdx.x * 4 + wv;
  if (d >= N) return;
  __shared__ float lds_p[4][64 * 9];
  __shared__ int   lds_s[4][64];
  float* lp = lds_p[wv];
  int*   ls = lds_s[wv];
  unsigned beg = off_[d], fin = cur[d];

  const float4* adp = (const float4*)(ad_ + (size_t)d * 8);
  float4 B0 = adp[0], B1 = adp[1];
  float adv[8] = {B0.x, B0.y, B0.z, B0.w, B1.x, B1.y, B1.z, B1.w};

  int c0 = lane & 31;        // dword index: channels 2c0, 2c0+1
  int pe = lane >> 5;        // edge parity
  int hh = c0 >> 2;          // head of channel pair
  float ps[8] = {0.f,0.f,0.f,0.f,0.f,0.f,0.f,0.f};
  float accx = 0.f, accy = 0.f;

  for (unsigned base = beg; base < fin; base += 64){
    unsigned i = base + lane;
    int nthis = (int)min(64u, fin - base);
    if (i < fin){
      int s = srcids[i];
      ls[lane] = s;
      const float4* ap = (const float4*)(as_ + (size_t)s * 8);
      float4 A0 = ap[0], A1 = ap[1];
      float ev[8] = {A0.x, A0.y, A0.z, A0.w, A1.x, A1.y, A1.z, A1.w};
      #pragma unroll
      for (int h = 0; h < 8; h++){
        float p = __expf(lrelu(ev[h] + adv[h]));
        ps[h] += p;
        lp[lane * 9 + h] = p;
      }
    } else {
      ls[lane] = 0;
      #pragma unroll
      for (int h = 0; h < 8; h++) lp[lane * 9 + h] = 0.f;
    }
    asm volatile("s_waitcnt lgkmcnt(0)" ::: "memory");
    __builtin_amdgcn_sched_barrier(0);
    for (int e = 0; e < nthis; e += 2){
      int ee = e + pe;                         // zero-padded when nthis odd
      float pv = lp[ee * 9 + hh];
      int se = ls[ee];
      unsigned u = *(const unsigned*)(h1b + (size_t)se * 64 + c0 * 2);
      accx = fmaf(pv, __uint_as_float(u << 16), accx);
      accy = fmaf(pv, __uint_as_float(u & 0xFFFF0000u), accy);
    }
    asm volatile("" ::: "memory");
  }
  #pragma unroll
  for (int h = 0; h < 8; h++) ps[h] = wred_sum(ps[h]);
  float den = ps[0];
  #pragma unroll
  for (int h = 1; h < 8; h++) den = (hh == h) ? ps[h] : den;

  accx += __shfl_xor(accx, 32, 64);
  accy += __shfl_xor(accy, 32, 64);
  if (lane < 32){
    int ch = lane * 2;
    float v0 = accx / den + b1[ch];
    float v1 = accy / den + b1[ch + 1];
    float2 o; o.x = v0 > 0.f ? v0 : 0.f; o.y = v1 > 0.f ? v1 : 0.f;
    *(float2*)(out1 + (size_t)d * 64 + ch) = o;
  }
}

// ============ GEMM2: h2 = out1 @ W2 -> bf16 ============
__global__ void k_gemm2(const float* __restrict__ in, const float* __restrict__ W,
                        unsigned short* __restrict__ h2b, int N){
  int i = blockIdx.x * blockDim.x + threadIdx.x;
  if (i >= N * 40) return;
  int c = i % 40, n = i / 40;
  const float* r = in + (size_t)n * 64;
  float acc = 0.f;
  #pragma unroll 8
  for (int k = 0; k < 64; k++) acc = fmaf(r[k], W[k * 40 + c], acc);
  h2b[i] = f2bf(acc);
}

__global__ void k_alpha2(const unsigned short* __restrict__ h2b, const float* __restrict__ asrc,
                         const float* __restrict__ adst, float* __restrict__ as_,
                         float* __restrict__ ad_, int N){
  int n = blockIdx.x * blockDim.x + threadIdx.x;
  if (n >= N) return;
  const unsigned* r = (const unsigned*)(h2b + (size_t)n * 40);
  float s = 0.f, d = 0.f;
  #pragma unroll
  for (int j = 0; j < 20; j++){
    unsigned u = r[j];
    float lo = __uint_as_float(u << 16);
    float hi = __uint_as_float(u & 0xFFFF0000u);
    s = fmaf(lo, asrc[2*j], fmaf(hi, asrc[2*j+1], s));
    d = fmaf(lo, adst[2*j], fmaf(hi, adst[2*j+1], d));
  }
  as_[n] = s; ad_[n] = d;
}

// ============ layer-2 per-dst gather (H=1, C=40), no max, bf16 messages ============
__global__ __launch_bounds__(256) void k_gat2(const unsigned* __restrict__ off_, const unsigned* __restrict__ cur,
    const int* __restrict__ srcids, const float* __restrict__ as_, const float* __restrict__ ad_,
    const unsigned short* __restrict__ h2b, float* __restrict__ out, int N){
  int lane = threadIdx.x & 63;
  int wv   = threadIdx.x >> 6;
  int d    = blockIdx.x * 4 + wv;
  if (d >= N) return;
  __shared__ float lds_p[4][64];
  __shared__ int   lds_s[4][64];
  float* lp = lds_p[wv];
  int*   ls = lds_s[wv];
  unsigned beg = off_[d], fin = cur[d];
  float add = ad_[d];

  int c0 = lane & 31;
  int pe = lane >> 5;
  int idx = c0 < 20 ? c0 : 19;
  float ps = 0.f, accx = 0.f, accy = 0.f;

  for (unsigned base = beg; base < fin; base += 64){
    unsigned i = base + lane;
    int nthis = (int)min(64u, fin - base);
    if (i < fin){
      int s = srcids[i];
      float p = __expf(lrelu(as_[s] + add));
      ps += p; ls[lane] = s; lp[lane] = p;
    } else { ls[lane] = 0; lp[lane] = 0.f; }
    asm volatile("s_waitcnt lgkmcnt(0)" ::: "memory");
    __builtin_amdgcn_sched_barrier(0);
    for (int e = 0; e < nthis; e += 2){
      int ee = e + pe;
      float pv = lp[ee];
      int se = ls[ee];
      unsigned u = *(const unsigned*)(h2b + (size_t)se * 40 + idx * 2);
      accx = fmaf(pv, __uint_as_float(u << 16), accx);
      accy = fmaf(pv, __uint_as_float(u & 0xFFFF0000u), accy);
    }
    asm volatile("" ::: "memory");
  }
  ps = wred_sum(ps);
  accx += __shfl_xor(accx, 32, 64);
  accy += __shfl_xor(accy, 32, 64);
  if (lane < 20){
    float2 o; o.x = accx / ps; o.y = accy / ps;
    *(float2*)(out + (size_t)d * 40 + lane * 2) = o;
  }
}

// ============ final: out = log_softmax(out + b2) ============
__global__ void k_lsm(float* __restrict__ out, const float* __restrict__ b, int N){
  int lane = threadIdx.x & 63;
  int row  = blockIdx.x * 4 + (threadIdx.x >> 6);
  if (row >= N) return;
  float v = (lane < 40) ? out[(size_t)row * 40 + lane] + b[lane] : -INFINITY;
  float mx = v;
  #pragma unroll
  for (int o = 32; o; o >>= 1) mx = fmaxf(mx, __shfl_xor(mx, o, 64));
  float ex = (lane < 40) ? __expf(v - mx) : 0.f;
  float sm = ex;
  #pragma unroll
  for (int o = 32; o; o >>= 1) sm += __shfl_xor(sm, o, 64);
  if (lane < 40) out[(size_t)row * 40 + lane] = v - mx - logf(sm);
}

extern "C" void kernel_launch(void* const* d_in, const int* in_sizes, int n_in,
                              void* d_out, int out_size, void* d_ws, size_t ws_size,
                              hipStream_t stream){
  const float* x   = (const float*)d_in[0];
  const int*   ei  = (const int*)d_in[1];
  const float* W1  = (const float*)d_in[2];
  const float* a1s = (const float*)d_in[3];
  const float* a1d = (const float*)d_in[4];
  const float* b1  = (const float*)d_in[5];
  const float* W2  = (const float*)d_in[6];
  const float* a2s = (const float*)d_in[7];
  const float* a2d = (const float*)d_in[8];
  const float* b2  = (const float*)d_in[9];
  float* out = (float*)d_out;

  const int N = in_sizes[0] / 256;
  const int E = in_sizes[1] / 2;

  float* ws = (float*)d_ws;
  size_t o = 0;
  float* as1  = ws + o; o += (size_t)N * 8;
  float* ad1  = ws + o; o += (size_t)N * 8;
  float* out1 = ws + o; o += (size_t)N * 64;                    // hosts scn during CSR build
  unsigned short* h1b = (unsigned short*)(ws + o); o += (size_t)N * 32;  // N*64 bf16
  unsigned short* h2b = (unsigned short*)(ws + o); o += (size_t)N * 20;  // N*40 bf16; hosts bsum
  unsigned* cnt  = (unsigned*)(ws + o); o += (size_t)N;
  unsigned* off_ = (unsigned*)(ws + o); o += (size_t)N;
  int* srcids    = (int*)(ws + o);      o += (size_t)(E + N);
  short* wt_hi   = (short*)(ws + o);    o += 8192;              // 16384 bf16
  short* wt_lo   = (short*)(ws + o);    o += 8192;
  unsigned* scn  = (unsigned*)out1;
  unsigned* bsum = (unsigned*)h2b;
  float* as2 = as1;
  float* ad2 = ad1;

  const int tot = E + N;
  const int tb  = (tot + 255) / 256;
  const int nb1 = (N + 255) / 256;

  hipMemsetAsync(cnt, 0, sizeof(unsigned) * (size_t)N, stream);

  // CSR build
  k_hist <<<tb, 256, 0, stream>>>(ei, E, N, cnt);
  k_scan1<<<nb1, 256, 0, stream>>>(cnt, scn, bsum, N);
  k_scan2<<<1, 512, 0, stream>>>(bsum, nb1);
  k_scan3<<<nb1, 256, 0, stream>>>(scn, bsum, off_, cnt, N);
  k_fill <<<tb, 256, 0, stream>>>(ei, E, N, cnt, srcids);

  // layer 1
  k_wprep<<<64, 256, 0, stream>>>(W1, wt_hi, wt_lo);
  k_gemm1_mfma<<<(N + 63) / 64, 256, 0, stream>>>(x, wt_hi, wt_lo, a1s, a1d, h1b, as1, ad1, N);
  k_gat1 <<<(N + 3) / 4, 256, 0, stream>>>(off_, cnt, srcids, as1, ad1, h1b, b1, out1, N);

  // layer 2
  k_gemm2 <<<((size_t)N * 40 + 255) / 256, 256, 0, stream>>>(out1, W2, h2b, N);
  k_alpha2<<<(N + 255) / 256, 256, 0, stream>>>(h2b, a2s, a2d, as2, ad2, N);
  k_gat2  <<<(N + 3) / 4, 256, 0, stream>>>(off_, cnt, srcids, as2, ad2, h2b, out, N);
  k_lsm   <<<(N + 3) / 4, 256, 0, stream>>>(out, b2, N);
}

// Round 5
// 387.409 us; speedup vs baseline: 27.9382x; 1.3711x over previous
//
#include <hip/hip_runtime.h>
#include <math.h>

#define NEG_SLOPE 0.2f
__device__ __forceinline__ float lrelu(float x){ return x >= 0.f ? x : NEG_SLOPE * x; }

typedef __attribute__((ext_vector_type(8))) short bf16x8;
typedef __attribute__((ext_vector_type(4))) float f32x4;

__device__ __forceinline__ float wred_sum(float v){
  #pragma unroll
  for (int o = 32; o; o >>= 1) v += __shfl_xor(v, o, 64);
  return v;
}

__device__ __forceinline__ float bfhi_f(float f){
  return __uint_as_float(__float_as_uint(f) & 0xFFFF0000u);
}
// fp32 -> bf16 RTNE
__device__ __forceinline__ unsigned short f2bf(float f){
  unsigned u = __float_as_uint(f);
  unsigned r = u + 0x7FFFu + ((u >> 16) & 1u);
  return (unsigned short)(r >> 16);
}

// ================= bucketed CSR build =================
// buckets of 256 dst nodes; nb = ceil(N/256)

__global__ __launch_bounds__(256) void k_bincnt(const int* __restrict__ ei, int E, int N, int nb,
                                                unsigned* __restrict__ bcnt){
  __shared__ unsigned h[512];
  const int tot = E + N;
  for (int i = threadIdx.x; i < nb; i += 256) h[i] = 0;
  __syncthreads();
  int base = blockIdx.x * 8192;
  #pragma unroll 4
  for (int j = 0; j < 32; j++){
    int e = base + threadIdx.x + j * 256;
    if (e < tot){
      unsigned d = (e < E) ? (unsigned)ei[E + e] : (unsigned)(e - E);
      atomicAdd(&h[d >> 8], 1u);
    }
  }
  __syncthreads();
  for (int i = threadIdx.x; i < nb; i += 256)
    if (h[i]) atomicAdd(&bcnt[i], h[i]);
}

__global__ void k_bscan(const unsigned* __restrict__ bcnt, unsigned* __restrict__ bbase,
                        unsigned* __restrict__ bcur, int nb, int tot){
  __shared__ unsigned s[512];
  int t = threadIdx.x;
  unsigned v = (t < nb) ? bcnt[t] : 0u;
  s[t] = v; __syncthreads();
  for (int off = 1; off < 512; off <<= 1){
    unsigned x = (t >= off) ? s[t - off] : 0u; __syncthreads();
    s[t] += x; __syncthreads();
  }
  if (t < nb){ unsigned b = s[t] - v; bbase[t] = b; bcur[t] = b; }
  if (t == 0) bbase[nb] = (unsigned)tot;
}

__global__ __launch_bounds__(256) void k_binscat(const int* __restrict__ ei, int E, int N, int nb,
    unsigned* __restrict__ bcur, unsigned* __restrict__ staged){
  __shared__ unsigned sd[8192];
  __shared__ unsigned hist[512];
  __shared__ unsigned runb[512];
  const int tot = E + N;
  for (int i = threadIdx.x; i < nb; i += 256) hist[i] = 0;
  __syncthreads();
  int base = blockIdx.x * 8192;
  #pragma unroll 4
  for (int j = 0; j < 32; j++){
    int idx = threadIdx.x + j * 256;
    int e = base + idx;
    unsigned d = 0xFFFFFFFFu;
    if (e < tot) d = (e < E) ? (unsigned)ei[E + e] : (unsigned)(e - E);
    sd[idx] = d;
    if (d != 0xFFFFFFFFu) atomicAdd(&hist[d >> 8], 1u);
  }
  __syncthreads();
  for (int i = threadIdx.x; i < nb; i += 256){
    unsigned c = hist[i];
    runb[i] = c ? atomicAdd(&bcur[i], c) : 0u;
    hist[i] = 0;
  }
  __syncthreads();
  #pragma unroll 4
  for (int j = 0; j < 32; j++){
    int idx = threadIdx.x + j * 256;
    unsigned d = sd[idx];
    if (d == 0xFFFFFFFFu) continue;
    int e = base + idx;
    unsigned s = (e < E) ? (unsigned)ei[e] : d;
    unsigned b = d >> 8;
    unsigned pos = runb[b] + atomicAdd(&hist[b], 1u);
    staged[pos] = s | ((d & 255u) << 20);      // src in bits 0..19, dloc in 20..27
  }
}

__global__ __launch_bounds__(256) void k_csr(const unsigned* __restrict__ bbase,
    const unsigned* __restrict__ staged, int N,
    unsigned* __restrict__ off_, unsigned* __restrict__ cur, int* __restrict__ srcids){
  __shared__ unsigned cnt[256], scn[256], cnt2[256];
  int b = blockIdx.x, t = threadIdx.x;
  unsigned beg = bbase[b], end = bbase[b + 1];
  cnt[t] = 0; cnt2[t] = 0;
  __syncthreads();
  for (unsigned i = beg + t; i < end; i += 256)
    atomicAdd(&cnt[staged[i] >> 20], 1u);
  __syncthreads();
  unsigned v = cnt[t];
  scn[t] = v; __syncthreads();
  for (int off = 1; off < 256; off <<= 1){
    unsigned x = (t >= off) ? scn[t - off] : 0u; __syncthreads();
    scn[t] += x; __syncthreads();
  }
  unsigned ex = scn[t] - v;
  int d = b * 256 + t;
  if (d < N){ off_[d] = beg + ex; cur[d] = beg + ex + v; }
  cnt[t] = ex;            // repurpose as exclusive-scan table
  __syncthreads();
  for (unsigned i = beg + t; i < end; i += 256){
    unsigned u = staged[i];
    unsigned dl = u >> 20;
    unsigned pos = beg + cnt[dl] + atomicAdd(&cnt2[dl], 1u);
    srcids[pos] = (int)(u & 0xFFFFFu);
  }
}

// ============ W prep: Wt_hi/Wt_lo[64][256] bf16 = transpose+split of W[256][64] ============
__global__ void k_wprep(const float* __restrict__ W, short* __restrict__ wt_hi,
                        short* __restrict__ wt_lo){
  int i = blockIdx.x * 256 + threadIdx.x;    // 16384
  int k = i >> 6, c = i & 63;
  float v = W[i];
  unsigned u = __float_as_uint(v);
  short hi = (short)(u >> 16);
  float lo = v - bfhi_f(v);
  wt_hi[c * 256 + k] = hi;
  wt_lo[c * 256 + k] = (short)(__float_as_uint(lo) >> 16);
}

// ============ GEMM1 via MFMA (hi/lo split) + fused alpha1 + bf16 h1 write ============
__global__ __launch_bounds__(256) void k_gemm1_mfma(const float* __restrict__ x,
    const short* __restrict__ wt_hi, const short* __restrict__ wt_lo,
    const float* __restrict__ a1s, const float* __restrict__ a1d,
    unsigned short* __restrict__ h1b, float* __restrict__ as_, float* __restrict__ ad_, int N){
  int lane = threadIdx.x & 63;
  int wv   = threadIdx.x >> 6;
  int r0   = blockIdx.x * 64 + wv * 16;
  if (r0 >= N) return;
  int col16 = lane & 15;
  int kg    = lane >> 4;
  const float* xr = x + (size_t)min(r0 + col16, N - 1) * 256 + kg * 8;

  f32x4 acc[4];
  #pragma unroll
  for (int ct = 0; ct < 4; ct++) acc[ct] = (f32x4){0.f, 0.f, 0.f, 0.f};

  #pragma unroll 2
  for (int kt = 0; kt < 8; kt++){
    float4 v0 = *(const float4*)(xr + kt * 32);
    float4 v1 = *(const float4*)(xr + kt * 32 + 4);
    unsigned u[8] = {__float_as_uint(v0.x), __float_as_uint(v0.y), __float_as_uint(v0.z), __float_as_uint(v0.w),
                     __float_as_uint(v1.x), __float_as_uint(v1.y), __float_as_uint(v1.z), __float_as_uint(v1.w)};
    union { bf16x8 v; unsigned u[4]; } ahi, alo;
    #pragma unroll
    for (int j = 0; j < 4; j++)
      ahi.u[j] = __builtin_amdgcn_perm(u[2*j+1], u[2*j], 0x07060302);
    float lo[8];
    lo[0] = v0.x - bfhi_f(v0.x); lo[1] = v0.y - bfhi_f(v0.y);
    lo[2] = v0.z - bfhi_f(v0.z); lo[3] = v0.w - bfhi_f(v0.w);
    lo[4] = v1.x - bfhi_f(v1.x); lo[5] = v1.y - bfhi_f(v1.y);
    lo[6] = v1.z - bfhi_f(v1.z); lo[7] = v1.w - bfhi_f(v1.w);
    #pragma unroll
    for (int j = 0; j < 4; j++)
      alo.u[j] = __builtin_amdgcn_perm(__float_as_uint(lo[2*j+1]), __float_as_uint(lo[2*j]), 0x07060302);

    #pragma unroll
    for (int ct = 0; ct < 4; ct++){
      int wcol = ct * 16 + col16;
      const bf16x8 bhi = *(const bf16x8*)(wt_hi + wcol * 256 + kt * 32 + kg * 8);
      const bf16x8 blo = *(const bf16x8*)(wt_lo + wcol * 256 + kt * 32 + kg * 8);
      acc[ct] = __builtin_amdgcn_mfma_f32_16x16x32_bf16(ahi.v, bhi, acc[ct], 0, 0, 0);
      acc[ct] = __builtin_amdgcn_mfma_f32_16x16x32_bf16(ahi.v, blo, acc[ct], 0, 0, 0);
      acc[ct] = __builtin_amdgcn_mfma_f32_16x16x32_bf16(alo.v, bhi, acc[ct], 0, 0, 0);
    }
  }

  float cs[4], cd[4];
  #pragma unroll
  for (int ct = 0; ct < 4; ct++){ cs[ct] = a1s[ct * 16 + col16]; cd[ct] = a1d[ct * 16 + col16]; }
  #pragma unroll
  for (int r = 0; r < 4; r++){
    int rr = r0 + kg * 4 + r;
    bool ok = rr < N;
    #pragma unroll
    for (int ct = 0; ct < 4; ct++){
      float v = acc[ct][r];
      if (ok) h1b[(size_t)rr * 64 + ct * 16 + col16] = f2bf(v);
      float s = v * cs[ct];
      float t = v * cd[ct];
      s += __shfl_xor(s, 1, 64); s += __shfl_xor(s, 2, 64); s += __shfl_xor(s, 4, 64);
      t += __shfl_xor(t, 1, 64); t += __shfl_xor(t, 2, 64); t += __shfl_xor(t, 4, 64);
      if (ok && (col16 & 7) == 0){
        int head = ct * 2 + (col16 >> 3);
        as_[(size_t)rr * 8 + head] = s;
        ad_[(size_t)rr * 8 + head] = t;
      }
    }
  }
}

// ============ layer-1 per-dst gather: single pass, no max, bf16 messages ============
__global__ __launch_bounds__(256) void k_gat1(const unsigned* __restrict__ off_, const unsigned* __restrict__ cur,
    const int* __restrict__ srcids, const float* __restrict__ as_, const float* __restrict__ ad_,
    const unsigned short* __restrict__ h1b, const float* __restrict__ b1, float* __restrict__ out1, int N){
  int lane = threadIdx.x & 63;
  int wv   = threadIdx.x >> 6;
  int d    = blockIdx.x * 4 + wv;
  if (d >= N) return;
  __shared__ float lds_p[4][64 * 9];
  __shared__ int   lds_s[4][64];
  float* lp = lds_p[wv];
  int*   ls = lds_s[wv];
  unsigned beg = off_[d], fin = cur[d];

  const float4* adp = (const float4*)(ad_ + (size_t)d * 8);
  float4 B0 = adp[0], B1 = adp[1];
  float adv[8] = {B0.x, B0.y, B0.z, B0.w, B1.x, B1.y, B1.z, B1.w};

  int c0 = lane & 31;
  int pe = lane >> 5;
  int hh = c0 >> 2;
  float ps[8] = {0.f,0.f,0.f,0.f,0.f,0.f,0.f,0.f};
  float accx = 0.f, accy = 0.f;

  for (unsigned base = beg; base < fin; base += 64){
    unsigned i = base + lane;
    int nthis = (int)min(64u, fin - base);
    if (i < fin){
      int s = srcids[i];
      ls[lane] = s;
      const float4* ap = (const float4*)(as_ + (size_t)s * 8);
      float4 A0 = ap[0], A1 = ap[1];
      float ev[8] = {A0.x, A0.y, A0.z, A0.w, A1.x, A1.y, A1.z, A1.w};
      #pragma unroll
      for (int h = 0; h < 8; h++){
        float p = __expf(lrelu(ev[h] + adv[h]));
        ps[h] += p;
        lp[lane * 9 + h] = p;
      }
    } else {
      ls[lane] = 0;
      #pragma unroll
      for (int h = 0; h < 8; h++) lp[lane * 9 + h] = 0.f;
    }
    asm volatile("s_waitcnt lgkmcnt(0)" ::: "memory");
    __builtin_amdgcn_sched_barrier(0);
    for (int e = 0; e < nthis; e += 2){
      int ee = e + pe;
      float pv = lp[ee * 9 + hh];
      int se = ls[ee];
      unsigned u = *(const unsigned*)(h1b + (size_t)se * 64 + c0 * 2);
      accx = fmaf(pv, __uint_as_float(u << 16), accx);
      accy = fmaf(pv, __uint_as_float(u & 0xFFFF0000u), accy);
    }
    asm volatile("" ::: "memory");
  }
  #pragma unroll
  for (int h = 0; h < 8; h++) ps[h] = wred_sum(ps[h]);
  float den = ps[0];
  #pragma unroll
  for (int h = 1; h < 8; h++) den = (hh == h) ? ps[h] : den;

  accx += __shfl_xor(accx, 32, 64);
  accy += __shfl_xor(accy, 32, 64);
  if (lane < 32){
    int ch = lane * 2;
    float v0 = accx / den + b1[ch];
    float v1 = accy / den + b1[ch + 1];
    float2 o; o.x = v0 > 0.f ? v0 : 0.f; o.y = v1 > 0.f ? v1 : 0.f;
    *(float2*)(out1 + (size_t)d * 64 + ch) = o;
  }
}

// ============ GEMM2: h2 = out1 @ W2 -> bf16 ============
__global__ void k_gemm2(const float* __restrict__ in, const float* __restrict__ W,
                        unsigned short* __restrict__ h2b, int N){
  int i = blockIdx.x * blockDim.x + threadIdx.x;
  if (i >= N * 40) return;
  int c = i % 40, n = i / 40;
  const float* r = in + (size_t)n * 64;
  float acc = 0.f;
  #pragma unroll 8
  for (int k = 0; k < 64; k++) acc = fmaf(r[k], W[k * 40 + c], acc);
  h2b[i] = f2bf(acc);
}

__global__ void k_alpha2(const unsigned short* __restrict__ h2b, const float* __restrict__ asrc,
                         const float* __restrict__ adst, float* __restrict__ as_,
                         float* __restrict__ ad_, int N){
  int n = blockIdx.x * blockDim.x + threadIdx.x;
  if (n >= N) return;
  const unsigned* r = (const unsigned*)(h2b + (size_t)n * 40);
  float s = 0.f, d = 0.f;
  #pragma unroll
  for (int j = 0; j < 20; j++){
    unsigned u = r[j];
    float lo = __uint_as_float(u << 16);
    float hi = __uint_as_float(u & 0xFFFF0000u);
    s = fmaf(lo, asrc[2*j], fmaf(hi, asrc[2*j+1], s));
    d = fmaf(lo, adst[2*j], fmaf(hi, adst[2*j+1], d));
  }
  as_[n] = s; ad_[n] = d;
}

// ============ layer-2 per-dst gather (H=1, C=40), no max, bf16 messages ============
__global__ __launch_bounds__(256) void k_gat2(const unsigned* __restrict__ off_, const unsigned* __restrict__ cur,
    const int* __restrict__ srcids, const float* __restrict__ as_, const float* __restrict__ ad_,
    const unsigned short* __restrict__ h2b, float* __restrict__ out, int N){
  int lane = threadIdx.x & 63;
  int wv   = threadIdx.x >> 6;
  int d    = blockIdx.x * 4 + wv;
  if (d >= N) return;
  __shared__ float lds_p[4][64];
  __shared__ int   lds_s[4][64];
  float* lp = lds_p[wv];
  int*   ls = lds_s[wv];
  unsigned beg = off_[d], fin = cur[d];
  float add = ad_[d];

  int c0 = lane & 31;
  int pe = lane >> 5;
  int idx = c0 < 20 ? c0 : 19;
  float ps = 0.f, accx = 0.f, accy = 0.f;

  for (unsigned base = beg; base < fin; base += 64){
    unsigned i = base + lane;
    int nthis = (int)min(64u, fin - base);
    if (i < fin){
      int s = srcids[i];
      float p = __expf(lrelu(as_[s] + add));
      ps += p; ls[lane] = s; lp[lane] = p;
    } else { ls[lane] = 0; lp[lane] = 0.f; }
    asm volatile("s_waitcnt lgkmcnt(0)" ::: "memory");
    __builtin_amdgcn_sched_barrier(0);
    for (int e = 0; e < nthis; e += 2){
      int ee = e + pe;
      float pv = lp[ee];
      int se = ls[ee];
      unsigned u = *(const unsigned*)(h2b + (size_t)se * 40 + idx * 2);
      accx = fmaf(pv, __uint_as_float(u << 16), accx);
      accy = fmaf(pv, __uint_as_float(u & 0xFFFF0000u), accy);
    }
    asm volatile("" ::: "memory");
  }
  ps = wred_sum(ps);
  accx += __shfl_xor(accx, 32, 64);
  accy += __shfl_xor(accy, 32, 64);
  if (lane < 20){
    float2 o; o.x = accx / ps; o.y = accy / ps;
    *(float2*)(out + (size_t)d * 40 + lane * 2) = o;
  }
}

// ============ final: out = log_softmax(out + b2) ============
__global__ void k_lsm(float* __restrict__ out, const float* __restrict__ b, int N){
  int lane = threadIdx.x & 63;
  int row  = blockIdx.x * 4 + (threadIdx.x >> 6);
  if (row >= N) return;
  float v = (lane < 40) ? out[(size_t)row * 40 + lane] + b[lane] : -INFINITY;
  float mx = v;
  #pragma unroll
  for (int o = 32; o; o >>= 1) mx = fmaxf(mx, __shfl_xor(mx, o, 64));
  float ex = (lane < 40) ? __expf(v - mx) : 0.f;
  float sm = ex;
  #pragma unroll
  for (int o = 32; o; o >>= 1) sm += __shfl_xor(sm, o, 64);
  if (lane < 40) out[(size_t)row * 40 + lane] = v - mx - logf(sm);
}

extern "C" void kernel_launch(void* const* d_in, const int* in_sizes, int n_in,
                              void* d_out, int out_size, void* d_ws, size_t ws_size,
                              hipStream_t stream){
  const float* x   = (const float*)d_in[0];
  const int*   ei  = (const int*)d_in[1];
  const float* W1  = (const float*)d_in[2];
  const float* a1s = (const float*)d_in[3];
  const float* a1d = (const float*)d_in[4];
  const float* b1  = (const float*)d_in[5];
  const float* W2  = (const float*)d_in[6];
  const float* a2s = (const float*)d_in[7];
  const float* a2d = (const float*)d_in[8];
  const float* b2  = (const float*)d_in[9];
  float* out = (float*)d_out;

  const int N = in_sizes[0] / 256;
  const int E = in_sizes[1] / 2;
  const int tot = E + N;
  const int nb  = (N + 255) >> 8;            // 256 dst-nodes per bucket

  float* ws = (float*)d_ws;
  size_t o = 0;
  float* as1  = ws + o; o += (size_t)N * 8;
  float* ad1  = ws + o; o += (size_t)N * 8;
  float* out1 = ws + o; o += (size_t)N * 64;                    // aliases `staged` during CSR build
  unsigned short* h1b = (unsigned short*)(ws + o); o += (size_t)N * 32;  // N*64 bf16
  unsigned short* h2b = (unsigned short*)(ws + o); o += (size_t)N * 20;  // N*40 bf16
  unsigned* off_ = (unsigned*)(ws + o); o += (size_t)N;
  unsigned* cur  = (unsigned*)(ws + o); o += (size_t)N;
  int* srcids    = (int*)(ws + o);      o += (size_t)tot;
  short* wt_hi   = (short*)(ws + o);    o += 8192;
  short* wt_lo   = (short*)(ws + o);    o += 8192;
  unsigned* bcnt  = (unsigned*)(ws + o); o += nb;
  unsigned* bbase = (unsigned*)(ws + o); o += nb + 1;
  unsigned* bcur  = (unsigned*)(ws + o); o += nb;
  unsigned* staged = (unsigned*)out1;
  float* as2 = as1;
  float* ad2 = ad1;

  const int cb = (tot + 8191) / 8192;        // chunk blocks for bin kernels

  hipMemsetAsync(bcnt, 0, sizeof(unsigned) * (size_t)nb, stream);

  // bucketed CSR build
  k_bincnt <<<cb, 256, 0, stream>>>(ei, E, N, nb, bcnt);
  k_bscan  <<<1, 512, 0, stream>>>(bcnt, bbase, bcur, nb, tot);
  k_binscat<<<cb, 256, 0, stream>>>(ei, E, N, nb, bcur, staged);
  k_csr    <<<nb, 256, 0, stream>>>(bbase, staged, N, off_, cur, srcids);

  // layer 1
  k_wprep<<<64, 256, 0, stream>>>(W1, wt_hi, wt_lo);
  k_gemm1_mfma<<<(N + 63) / 64, 256, 0, stream>>>(x, wt_hi, wt_lo, a1s, a1d, h1b, as1, ad1, N);
  k_gat1 <<<(N + 3) / 4, 256, 0, stream>>>(off_, cur, srcids, as1, ad1, h1b, b1, out1, N);

  // layer 2
  k_gemm2 <<<((size_t)N * 40 + 255) / 256, 256, 0, stream>>>(out1, W2, h2b, N);
  k_alpha2<<<(N + 255) / 256, 256, 0, stream>>>(h2b, a2s, a2d, as2, ad2, N);
  k_gat2  <<<(N + 3) / 4, 256, 0, stream>>>(off_, cur, srcids, as2, ad2, h2b, out, N);
  k_lsm   <<<(N + 3) / 4, 256, 0, stream>>>(out, b2, N);
}

// Round 7
// 338.919 us; speedup vs baseline: 31.9354x; 1.1431x over previous
//
#include <hip/hip_runtime.h>
#include <math.h>

#define NEG_SLOPE 0.2f
__device__ __forceinline__ float lrelu(float x){ return x >= 0.f ? x : NEG_SLOPE * x; }

typedef __attribute__((ext_vector_type(8))) short bf16x8;
typedef __attribute__((ext_vector_type(4))) float f32x4;

__device__ __forceinline__ float wred_sum(float v){
  #pragma unroll
  for (int o = 32; o; o >>= 1) v += __shfl_xor(v, o, 64);
  return v;
}

__device__ __forceinline__ float bfhi_f(float f){
  return __uint_as_float(__float_as_uint(f) & 0xFFFF0000u);
}
// fp32 -> bf16 RTNE
__device__ __forceinline__ unsigned short f2bf(float f){
  unsigned u = __float_as_uint(f);
  unsigned r = u + 0x7FFFu + ((u >> 16) & 1u);
  return (unsigned short)(r >> 16);
}

// ================= bucketed CSR build =================
__global__ __launch_bounds__(256) void k_bincnt(const int* __restrict__ ei, int E, int N, int nb,
                                                unsigned* __restrict__ bcnt){
  __shared__ unsigned h[512];
  const int tot = E + N;
  for (int i = threadIdx.x; i < nb; i += 256) h[i] = 0;
  __syncthreads();
  int base = blockIdx.x * 8192;
  #pragma unroll 4
  for (int j = 0; j < 32; j++){
    int e = base + threadIdx.x + j * 256;
    if (e < tot){
      unsigned d = (e < E) ? (unsigned)ei[E + e] : (unsigned)(e - E);
      atomicAdd(&h[d >> 8], 1u);
    }
  }
  __syncthreads();
  for (int i = threadIdx.x; i < nb; i += 256)
    if (h[i]) atomicAdd(&bcnt[i], h[i]);
}

__global__ void k_bscan(const unsigned* __restrict__ bcnt, unsigned* __restrict__ bbase,
                        unsigned* __restrict__ bcur, int nb, int tot){
  __shared__ unsigned s[512];
  int t = threadIdx.x;
  unsigned v = (t < nb) ? bcnt[t] : 0u;
  s[t] = v; __syncthreads();
  for (int off = 1; off < 512; off <<= 1){
    unsigned x = (t >= off) ? s[t - off] : 0u; __syncthreads();
    s[t] += x; __syncthreads();
  }
  if (t < nb){ unsigned b = s[t] - v; bbase[t] = b; bcur[t] = b; }
  if (t == 0) bbase[nb] = (unsigned)tot;
}

__global__ __launch_bounds__(256) void k_binscat(const int* __restrict__ ei, int E, int N, int nb,
    unsigned* __restrict__ bcur, unsigned* __restrict__ staged){
  __shared__ unsigned sd[8192];
  __shared__ unsigned hist[512];
  __shared__ unsigned runb[512];
  const int tot = E + N;
  for (int i = threadIdx.x; i < nb; i += 256) hist[i] = 0;
  __syncthreads();
  int base = blockIdx.x * 8192;
  #pragma unroll 4
  for (int j = 0; j < 32; j++){
    int idx = threadIdx.x + j * 256;
    int e = base + idx;
    unsigned d = 0xFFFFFFFFu;
    if (e < tot) d = (e < E) ? (unsigned)ei[E + e] : (unsigned)(e - E);
    sd[idx] = d;
    if (d != 0xFFFFFFFFu) atomicAdd(&hist[d >> 8], 1u);
  }
  __syncthreads();
  for (int i = threadIdx.x; i < nb; i += 256){
    unsigned c = hist[i];
    runb[i] = c ? atomicAdd(&bcur[i], c) : 0u;
    hist[i] = 0;
  }
  __syncthreads();
  #pragma unroll 4
  for (int j = 0; j < 32; j++){
    int idx = threadIdx.x + j * 256;
    unsigned d = sd[idx];
    if (d == 0xFFFFFFFFu) continue;
    int e = base + idx;
    unsigned s = (e < E) ? (unsigned)ei[e] : d;
    unsigned b = d >> 8;
    unsigned pos = runb[b] + atomicAdd(&hist[b], 1u);
    staged[pos] = s | ((d & 255u) << 20);
  }
}

__global__ __launch_bounds__(256) void k_csr(const unsigned* __restrict__ bbase,
    const unsigned* __restrict__ staged, int N,
    unsigned* __restrict__ off_, unsigned* __restrict__ cur, int* __restrict__ srcids){
  __shared__ unsigned cnt[256], scn[256], cnt2[256];
  int b = blockIdx.x, t = threadIdx.x;
  unsigned beg = bbase[b], end = bbase[b + 1];
  cnt[t] = 0; cnt2[t] = 0;
  __syncthreads();
  for (unsigned i = beg + t; i < end; i += 256)
    atomicAdd(&cnt[staged[i] >> 20], 1u);
  __syncthreads();
  unsigned v = cnt[t];
  scn[t] = v; __syncthreads();
  for (int off = 1; off < 256; off <<= 1){
    unsigned x = (t >= off) ? scn[t - off] : 0u; __syncthreads();
    scn[t] += x; __syncthreads();
  }
  unsigned ex = scn[t] - v;
  int d = b * 256 + t;
  if (d < N){ off_[d] = beg + ex; cur[d] = beg + ex + v; }
  cnt[t] = ex;
  __syncthreads();
  for (unsigned i = beg + t; i < end; i += 256){
    unsigned u = staged[i];
    unsigned dl = u >> 20;
    unsigned pos = beg + cnt[dl] + atomicAdd(&cnt2[dl], 1u);
    srcids[pos] = (int)(u & 0xFFFFFu);
  }
}

// ============ W1 prep: Wt_hi/Wt_lo[64][256] bf16 ============
__global__ void k_wprep(const float* __restrict__ W, short* __restrict__ wt_hi,
                        short* __restrict__ wt_lo){
  int i = blockIdx.x * 256 + threadIdx.x;    // 16384
  int k = i >> 6, c = i & 63;
  float v = W[i];
  unsigned u = __float_as_uint(v);
  wt_hi[c * 256 + k] = (short)(u >> 16);
  float lo = v - bfhi_f(v);
  wt_lo[c * 256 + k] = (short)(__float_as_uint(lo) >> 16);
}

// ============ W2 prep: [48][64] bf16 hi/lo (cols 40-47 zero) ============
__global__ void k_w2prep(const float* __restrict__ W2, short* __restrict__ hi,
                         short* __restrict__ lo){
  int i = blockIdx.x * 256 + threadIdx.x;    // 3072
  if (i >= 48 * 64) return;
  int c = i >> 6, k = i & 63;
  float v = (c < 40) ? W2[k * 40 + c] : 0.f;
  unsigned u = __float_as_uint(v);
  hi[c * 64 + k] = (short)(u >> 16);
  float l = v - bfhi_f(v);
  lo[c * 64 + k] = (short)(__float_as_uint(l) >> 16);
}

// ============ GEMM1 via MFMA (hi/lo split) + fused alpha1 + bf16 h1 write ============
__global__ __launch_bounds__(256) void k_gemm1_mfma(const float* __restrict__ x,
    const short* __restrict__ wt_hi, const short* __restrict__ wt_lo,
    const float* __restrict__ a1s, const float* __restrict__ a1d,
    unsigned short* __restrict__ h1b, float* __restrict__ as_, float* __restrict__ ad_, int N){
  int lane = threadIdx.x & 63;
  int wv   = threadIdx.x >> 6;
  int r0   = blockIdx.x * 64 + wv * 16;
  if (r0 >= N) return;
  int col16 = lane & 15;
  int kg    = lane >> 4;
  const float* xr = x + (size_t)min(r0 + col16, N - 1) * 256 + kg * 8;

  f32x4 acc[4];
  #pragma unroll
  for (int ct = 0; ct < 4; ct++) acc[ct] = (f32x4){0.f, 0.f, 0.f, 0.f};

  #pragma unroll 2
  for (int kt = 0; kt < 8; kt++){
    float4 v0 = *(const float4*)(xr + kt * 32);
    float4 v1 = *(const float4*)(xr + kt * 32 + 4);
    unsigned u[8] = {__float_as_uint(v0.x), __float_as_uint(v0.y), __float_as_uint(v0.z), __float_as_uint(v0.w),
                     __float_as_uint(v1.x), __float_as_uint(v1.y), __float_as_uint(v1.z), __float_as_uint(v1.w)};
    union { bf16x8 v; unsigned u[4]; } ahi, alo;
    #pragma unroll
    for (int j = 0; j < 4; j++)
      ahi.u[j] = __builtin_amdgcn_perm(u[2*j+1], u[2*j], 0x07060302);
    float lo[8];
    lo[0] = v0.x - bfhi_f(v0.x); lo[1] = v0.y - bfhi_f(v0.y);
    lo[2] = v0.z - bfhi_f(v0.z); lo[3] = v0.w - bfhi_f(v0.w);
    lo[4] = v1.x - bfhi_f(v1.x); lo[5] = v1.y - bfhi_f(v1.y);
    lo[6] = v1.z - bfhi_f(v1.z); lo[7] = v1.w - bfhi_f(v1.w);
    #pragma unroll
    for (int j = 0; j < 4; j++)
      alo.u[j] = __builtin_amdgcn_perm(__float_as_uint(lo[2*j+1]), __float_as_uint(lo[2*j]), 0x07060302);

    #pragma unroll
    for (int ct = 0; ct < 4; ct++){
      int wcol = ct * 16 + col16;
      const bf16x8 bhi = *(const bf16x8*)(wt_hi + wcol * 256 + kt * 32 + kg * 8);
      const bf16x8 blo = *(const bf16x8*)(wt_lo + wcol * 256 + kt * 32 + kg * 8);
      acc[ct] = __builtin_amdgcn_mfma_f32_16x16x32_bf16(ahi.v, bhi, acc[ct], 0, 0, 0);
      acc[ct] = __builtin_amdgcn_mfma_f32_16x16x32_bf16(ahi.v, blo, acc[ct], 0, 0, 0);
      acc[ct] = __builtin_amdgcn_mfma_f32_16x16x32_bf16(alo.v, bhi, acc[ct], 0, 0, 0);
    }
  }

  float cs[4], cd[4];
  #pragma unroll
  for (int ct = 0; ct < 4; ct++){ cs[ct] = a1s[ct * 16 + col16]; cd[ct] = a1d[ct * 16 + col16]; }
  #pragma unroll
  for (int r = 0; r < 4; r++){
    int rr = r0 + kg * 4 + r;
    bool ok = rr < N;
    #pragma unroll
    for (int ct = 0; ct < 4; ct++){
      float v = acc[ct][r];
      if (ok) h1b[(size_t)rr * 64 + ct * 16 + col16] = f2bf(v);
      float s = v * cs[ct];
      float t = v * cd[ct];
      s += __shfl_xor(s, 1, 64); s += __shfl_xor(s, 2, 64); s += __shfl_xor(s, 4, 64);
      t += __shfl_xor(t, 1, 64); t += __shfl_xor(t, 2, 64); t += __shfl_xor(t, 4, 64);
      if (ok && (col16 & 7) == 0){
        int head = ct * 2 + (col16 >> 3);
        as_[(size_t)rr * 8 + head] = s;
        ad_[(size_t)rr * 8 + head] = t;
      }
    }
  }
}

// ============ layer-1 per-dst gather: lane=(edge,head) exp layout, bf16 out ============
__global__ __launch_bounds__(256) void k_gat1(const unsigned* __restrict__ off_, const unsigned* __restrict__ cur,
    const int* __restrict__ srcids, const float* __restrict__ as_, const float* __restrict__ ad_,
    const unsigned short* __restrict__ h1b, const float* __restrict__ b1,
    unsigned short* __restrict__ out1b, int N){
  int lane = threadIdx.x & 63;
  int wv   = threadIdx.x >> 6;
  int d    = blockIdx.x * 4 + wv;
  if (d >= N) return;
  __shared__ float lds_p[4][64 * 8];
  __shared__ int   lds_s[4][64];
  float* lp = lds_p[wv];
  int*   ls = lds_s[wv];
  unsigned beg = off_[d], fin = cur[d];

  int e8 = lane >> 3, h = lane & 7;            // exp-phase layout
  int c0 = lane & 31, pe = lane >> 5, hh = c0 >> 2;  // channel-phase layout
  float adh = ad_[(size_t)d * 8 + h];
  float psacc = 0.f, accx = 0.f, accy = 0.f;

  for (unsigned base = beg; base < fin; base += 64){
    int nthis = (int)min(64u, fin - base);
    // exp sub-phase: 8 edges x 8 heads per iter, 1 exp per lane
    for (int j = 0; j < nthis; j += 8){
      int eloc = j + e8;
      bool valid = eloc < nthis;
      int s = valid ? srcids[base + eloc] : 0;
      if (h == 0) ls[eloc] = s;
      float p = 0.f;
      if (valid) p = __expf(lrelu(as_[(size_t)s * 8 + h] + adh));
      lp[eloc * 8 + h] = p;
      psacc += p;
    }
    asm volatile("s_waitcnt lgkmcnt(0)" ::: "memory");
    __builtin_amdgcn_sched_barrier(0);
    // channel phase: 32 dword-channels x 2 edges
    for (int e = 0; e < nthis; e += 2){
      int ee = e + pe;
      float pv = lp[ee * 8 + hh];
      int se = ls[ee];
      unsigned u = *(const unsigned*)(h1b + (size_t)se * 64 + c0 * 2);
      accx = fmaf(pv, __uint_as_float(u << 16), accx);
      accy = fmaf(pv, __uint_as_float(u & 0xFFFF0000u), accy);
    }
    asm volatile("" ::: "memory");
  }
  // per-head denominator: reduce over e8 groups (lanes with same h)
  float den = psacc;
  den += __shfl_xor(den, 8, 64);
  den += __shfl_xor(den, 16, 64);
  den += __shfl_xor(den, 32, 64);
  float mydenv = __shfl(den, hh, 64);          // lane hh holds head hh
  accx += __shfl_xor(accx, 32, 64);
  accy += __shfl_xor(accy, 32, 64);
  if (lane < 32){
    int ch = lane * 2;
    float v0 = accx / mydenv + b1[ch];
    float v1 = accy / mydenv + b1[ch + 1];
    ushort2 o;
    o.x = f2bf(v0 > 0.f ? v0 : 0.f);
    o.y = f2bf(v1 > 0.f ? v1 : 0.f);
    *(ushort2*)(out1b + (size_t)d * 64 + ch) = o;
  }
}

// ============ GEMM2 via MFMA (bf16 A, hi/lo B) + fused alpha2 ============
__global__ __launch_bounds__(256) void k_gemm2m(const unsigned short* __restrict__ out1b,
    const short* __restrict__ wt2_hi, const short* __restrict__ wt2_lo,
    const float* __restrict__ a2s, const float* __restrict__ a2d,
    unsigned short* __restrict__ h2b, float* __restrict__ as_, float* __restrict__ ad_, int N){
  int lane = threadIdx.x & 63;
  int wv   = threadIdx.x >> 6;
  int r0   = blockIdx.x * 64 + wv * 16;
  if (r0 >= N) return;
  int col16 = lane & 15;
  int kg    = lane >> 4;
  const unsigned short* ar = out1b + (size_t)min(r0 + col16, N - 1) * 64 + kg * 8;

  f32x4 acc[3];
  #pragma unroll
  for (int ct = 0; ct < 3; ct++) acc[ct] = (f32x4){0.f, 0.f, 0.f, 0.f};

  #pragma unroll
  for (int kt = 0; kt < 2; kt++){
    const bf16x8 a = *(const bf16x8*)(ar + kt * 32);
    #pragma unroll
    for (int ct = 0; ct < 3; ct++){
      int wcol = ct * 16 + col16;
      const bf16x8 bhi = *(const bf16x8*)(wt2_hi + wcol * 64 + kt * 32 + kg * 8);
      const bf16x8 blo = *(const bf16x8*)(wt2_lo + wcol * 64 + kt * 32 + kg * 8);
      acc[ct] = __builtin_amdgcn_mfma_f32_16x16x32_bf16(a, bhi, acc[ct], 0, 0, 0);
      acc[ct] = __builtin_amdgcn_mfma_f32_16x16x32_bf16(a, blo, acc[ct], 0, 0, 0);
    }
  }

  float cs[3], cd[3];
  #pragma unroll
  for (int ct = 0; ct < 3; ct++){
    int col = ct * 16 + col16;
    bool okc = col < 40;
    cs[ct] = okc ? a2s[col] : 0.f;
    cd[ct] = okc ? a2d[col] : 0.f;
  }
  #pragma unroll
  for (int r = 0; r < 4; r++){
    int rr = r0 + kg * 4 + r;
    bool ok = rr < N;
    float s = 0.f, t = 0.f;
    #pragma unroll
    for (int ct = 0; ct < 3; ct++){
      s = fmaf(acc[ct][r], cs[ct], s);
      t = fmaf(acc[ct][r], cd[ct], t);
      int col = ct * 16 + col16;
      if (ok && col < 40) h2b[(size_t)rr * 40 + col] = f2bf(acc[ct][r]);
    }
    s += __shfl_xor(s, 1, 64); s += __shfl_xor(s, 2, 64);
    s += __shfl_xor(s, 4, 64); s += __shfl_xor(s, 8, 64);
    t += __shfl_xor(t, 1, 64); t += __shfl_xor(t, 2, 64);
    t += __shfl_xor(t, 4, 64); t += __shfl_xor(t, 8, 64);
    if (ok && col16 == 0){ as_[rr] = s; ad_[rr] = t; }
  }
}

// ============ layer-2 per-dst gather (H=1, C=40) ============
__global__ __launch_bounds__(256) void k_gat2(const unsigned* __restrict__ off_, const unsigned* __restrict__ cur,
    const int* __restrict__ srcids, const float* __restrict__ as_, const float* __restrict__ ad_,
    const unsigned short* __restrict__ h2b, float* __restrict__ out, int N){
  int lane = threadIdx.x & 63;
  int wv   = threadIdx.x >> 6;
  int d    = blockIdx.x * 4 + wv;
  if (d >= N) return;
  __shared__ float lds_p[4][64];
  __shared__ int   lds_s[4][64];
  float* lp = lds_p[wv];
  int*   ls = lds_s[wv];
  unsigned beg = off_[d], fin = cur[d];
  float add = ad_[d];

  int c0 = lane & 31;
  int pe = lane >> 5;
  int idx = c0 < 20 ? c0 : 19;
  float ps = 0.f, accx = 0.f, accy = 0.f;

  for (unsigned base = beg; base < fin; base += 64){
    unsigned i = base + lane;
    int nthis = (int)min(64u, fin - base);
    if (i < fin){
      int s = srcids[i];
      float p = __expf(lrelu(as_[s] + add));
      ps += p; ls[lane] = s; lp[lane] = p;
    } else { ls[lane] = 0; lp[lane] = 0.f; }
    asm volatile("s_waitcnt lgkmcnt(0)" ::: "memory");
    __builtin_amdgcn_sched_barrier(0);
    for (int e = 0; e < nthis; e += 2){
      int ee = e + pe;
      float pv = lp[ee];
      int se = ls[ee];
      unsigned u = *(const unsigned*)(h2b + (size_t)se * 40 + idx * 2);
      accx = fmaf(pv, __uint_as_float(u << 16), accx);
      accy = fmaf(pv, __uint_as_float(u & 0xFFFF0000u), accy);
    }
    asm volatile("" ::: "memory");
  }
  ps = wred_sum(ps);
  accx += __shfl_xor(accx, 32, 64);
  accy += __shfl_xor(accy, 32, 64);
  if (lane < 20){
    float2 o; o.x = accx / ps; o.y = accy / ps;
    *(float2*)(out + (size_t)d * 40 + lane * 2) = o;
  }
}

// ============ final: out = log_softmax(out + b2) ============
__global__ void k_lsm(float* __restrict__ out, const float* __restrict__ b, int N){
  int lane = threadIdx.x & 63;
  int row  = blockIdx.x * 4 + (threadIdx.x >> 6);
  if (row >= N) return;
  float v = (lane < 40) ? out[(size_t)row * 40 + lane] + b[lane] : -INFINITY;
  float mx = v;
  #pragma unroll
  for (int o = 32; o; o >>= 1) mx = fmaxf(mx, __shfl_xor(mx, o, 64));
  float ex = (lane < 40) ? __expf(v - mx) : 0.f;
  float sm = ex;
  #pragma unroll
  for (int o = 32; o; o >>= 1) sm += __shfl_xor(sm, o, 64);
  if (lane < 40) out[(size_t)row * 40 + lane] = v - mx - logf(sm);
}

extern "C" void kernel_launch(void* const* d_in, const int* in_sizes, int n_in,
                              void* d_out, int out_size, void* d_ws, size_t ws_size,
                              hipStream_t stream){
  const float* x   = (const float*)d_in[0];
  const int*   ei  = (const int*)d_in[1];
  const float* W1  = (const float*)d_in[2];
  const float* a1s = (const float*)d_in[3];
  const float* a1d = (const float*)d_in[4];
  const float* b1  = (const float*)d_in[5];
  const float* W2  = (const float*)d_in[6];
  const float* a2s = (const float*)d_in[7];
  const float* a2d = (const float*)d_in[8];
  const float* b2  = (const float*)d_in[9];
  float* out = (float*)d_out;

  const int N = in_sizes[0] / 256;
  const int E = in_sizes[1] / 2;
  const int tot = E + N;
  const int nb  = (N + 255) >> 8;

  float* ws = (float*)d_ws;
  size_t o = 0;
  float* as1  = ws + o; o += (size_t)N * 8;
  float* ad1  = ws + o; o += (size_t)N * 8;
  unsigned short* out1b = (unsigned short*)(ws + o); o += (size_t)N * 32;  // aliases `staged`
  unsigned short* h1b   = (unsigned short*)(ws + o); o += (size_t)N * 32;
  unsigned short* h2b   = (unsigned short*)(ws + o); o += (size_t)N * 20;
  unsigned* off_ = (unsigned*)(ws + o); o += (size_t)N;
  unsigned* cur  = (unsigned*)(ws + o); o += (size_t)N;
  int* srcids    = (int*)(ws + o);      o += (size_t)tot;
  short* wt_hi   = (short*)(ws + o);    o += 8192;   // 16384 bf16
  short* wt_lo   = (short*)(ws + o);    o += 8192;
  short* wt2_hi  = (short*)(ws + o);    o += 1536;   // 3072 bf16 (48x64)
  short* wt2_lo  = (short*)(ws + o);    o += 1536;
  unsigned* bcnt  = (unsigned*)(ws + o); o += nb;
  unsigned* bbase = (unsigned*)(ws + o); o += nb + 1;
  unsigned* bcur  = (unsigned*)(ws + o); o += nb;
  unsigned* staged = (unsigned*)out1b;
  float* as2 = as1;
  float* ad2 = ad1;

  const int cb = (tot + 8191) / 8192;

  hipMemsetAsync(bcnt, 0, sizeof(unsigned) * (size_t)nb, stream);

  // bucketed CSR build
  k_bincnt <<<cb, 256, 0, stream>>>(ei, E, N, nb, bcnt);
  k_bscan  <<<1, 512, 0, stream>>>(bcnt, bbase, bcur, nb, tot);
  k_binscat<<<cb, 256, 0, stream>>>(ei, E, N, nb, bcur, staged);
  k_csr    <<<nb, 256, 0, stream>>>(bbase, staged, N, off_, cur, srcids);

  // weight prep
  k_wprep <<<64, 256, 0, stream>>>(W1, wt_hi, wt_lo);
  k_w2prep<<<12, 256, 0, stream>>>(W2, wt2_hi, wt2_lo);

  // layer 1
  k_gemm1_mfma<<<(N + 63) / 64, 256, 0, stream>>>(x, wt_hi, wt_lo, a1s, a1d, h1b, as1, ad1, N);
  k_gat1 <<<(N + 3) / 4, 256, 0, stream>>>(off_, cur, srcids, as1, ad1, h1b, b1, out1b, N);

  // layer 2
  k_gemm2m<<<(N + 63) / 64, 256, 0, stream>>>(out1b, wt2_hi, wt2_lo, a2s, a2d, h2b, as2, ad2, N);
  k_gat2  <<<(N + 3) / 4, 256, 0, stream>>>(off_, cur, srcids, as2, ad2, h2b, out, N);
  k_lsm   <<<(N + 3) / 4, 256, 0, stream>>>(out, b2, N);
}

// Round 8
// 267.297 us; speedup vs baseline: 40.4924x; 1.2679x over previous
//
#include <hip/hip_runtime.h>
#include <math.h>

#define NEG_SLOPE 0.2f
__device__ __forceinline__ float lrelu(float x){ return x >= 0.f ? x : NEG_SLOPE * x; }

typedef __attribute__((ext_vector_type(8))) short bf16x8;
typedef __attribute__((ext_vector_type(4))) float f32x4;

__device__ __forceinline__ float wred_sum(float v){
  #pragma unroll
  for (int o = 32; o; o >>= 1) v += __shfl_xor(v, o, 64);
  return v;
}

__device__ __forceinline__ float bfhi_f(float f){
  return __uint_as_float(__float_as_uint(f) & 0xFFFF0000u);
}
// fp32 -> bf16 RTNE
__device__ __forceinline__ unsigned short f2bf(float f){
  unsigned u = __float_as_uint(f);
  unsigned r = u + 0x7FFFu + ((u >> 16) & 1u);
  return (unsigned short)(r >> 16);
}

// ================= bucketed CSR build =================
__global__ __launch_bounds__(256) void k_bincnt(const int* __restrict__ ei, int E, int N, int nb,
                                                unsigned* __restrict__ bcnt){
  __shared__ unsigned h[512];
  const int tot = E + N;
  for (int i = threadIdx.x; i < nb; i += 256) h[i] = 0;
  __syncthreads();
  int base = blockIdx.x * 8192;
  #pragma unroll 4
  for (int j = 0; j < 32; j++){
    int e = base + threadIdx.x + j * 256;
    if (e < tot){
      unsigned d = (e < E) ? (unsigned)ei[E + e] : (unsigned)(e - E);
      atomicAdd(&h[d >> 8], 1u);
    }
  }
  __syncthreads();
  for (int i = threadIdx.x; i < nb; i += 256)
    if (h[i]) atomicAdd(&bcnt[i], h[i]);
}

__global__ void k_bscan(const unsigned* __restrict__ bcnt, unsigned* __restrict__ bbase,
                        unsigned* __restrict__ bcur, int nb, int tot){
  __shared__ unsigned s[512];
  int t = threadIdx.x;
  unsigned v = (t < nb) ? bcnt[t] : 0u;
  s[t] = v; __syncthreads();
  for (int off = 1; off < 512; off <<= 1){
    unsigned x = (t >= off) ? s[t - off] : 0u; __syncthreads();
    s[t] += x; __syncthreads();
  }
  if (t < nb){ unsigned b = s[t] - v; bbase[t] = b; bcur[t] = b; }
  if (t == 0) bbase[nb] = (unsigned)tot;
}

__global__ __launch_bounds__(256) void k_binscat(const int* __restrict__ ei, int E, int N, int nb,
    unsigned* __restrict__ bcur, unsigned* __restrict__ staged){
  __shared__ unsigned sd[8192];
  __shared__ unsigned hist[512];
  __shared__ unsigned runb[512];
  const int tot = E + N;
  for (int i = threadIdx.x; i < nb; i += 256) hist[i] = 0;
  __syncthreads();
  int base = blockIdx.x * 8192;
  #pragma unroll 4
  for (int j = 0; j < 32; j++){
    int idx = threadIdx.x + j * 256;
    int e = base + idx;
    unsigned d = 0xFFFFFFFFu;
    if (e < tot) d = (e < E) ? (unsigned)ei[E + e] : (unsigned)(e - E);
    sd[idx] = d;
    if (d != 0xFFFFFFFFu) atomicAdd(&hist[d >> 8], 1u);
  }
  __syncthreads();
  for (int i = threadIdx.x; i < nb; i += 256){
    unsigned c = hist[i];
    runb[i] = c ? atomicAdd(&bcur[i], c) : 0u;
    hist[i] = 0;
  }
  __syncthreads();
  #pragma unroll 4
  for (int j = 0; j < 32; j++){
    int idx = threadIdx.x + j * 256;
    unsigned d = sd[idx];
    if (d == 0xFFFFFFFFu) continue;
    int e = base + idx;
    unsigned s = (e < E) ? (unsigned)ei[e] : d;
    unsigned b = d >> 8;
    unsigned pos = runb[b] + atomicAdd(&hist[b], 1u);
    staged[pos] = s | ((d & 255u) << 20);
  }
}

__global__ __launch_bounds__(256) void k_csr(const unsigned* __restrict__ bbase,
    const unsigned* __restrict__ staged, int N,
    unsigned* __restrict__ off_, unsigned* __restrict__ cur, int* __restrict__ srcids){
  __shared__ unsigned cnt[256], scn[256], cnt2[256];
  int b = blockIdx.x, t = threadIdx.x;
  unsigned beg = bbase[b], end = bbase[b + 1];
  cnt[t] = 0; cnt2[t] = 0;
  __syncthreads();
  for (unsigned i = beg + t; i < end; i += 256)
    atomicAdd(&cnt[staged[i] >> 20], 1u);
  __syncthreads();
  unsigned v = cnt[t];
  scn[t] = v; __syncthreads();
  for (int off = 1; off < 256; off <<= 1){
    unsigned x = (t >= off) ? scn[t - off] : 0u; __syncthreads();
    scn[t] += x; __syncthreads();
  }
  unsigned ex = scn[t] - v;
  int d = b * 256 + t;
  if (d < N){ off_[d] = beg + ex; cur[d] = beg + ex + v; }
  cnt[t] = ex;
  __syncthreads();
  for (unsigned i = beg + t; i < end; i += 256){
    unsigned u = staged[i];
    unsigned dl = u >> 20;
    unsigned pos = beg + cnt[dl] + atomicAdd(&cnt2[dl], 1u);
    srcids[pos] = (int)(u & 0xFFFFFu);
  }
}

// ============ W1 prep: Wt_hi/Wt_lo[64][256] bf16 ============
__global__ void k_wprep(const float* __restrict__ W, short* __restrict__ wt_hi,
                        short* __restrict__ wt_lo){
  int i = blockIdx.x * 256 + threadIdx.x;    // 16384
  int k = i >> 6, c = i & 63;
  float v = W[i];
  unsigned u = __float_as_uint(v);
  wt_hi[c * 256 + k] = (short)(u >> 16);
  float lo = v - bfhi_f(v);
  wt_lo[c * 256 + k] = (short)(__float_as_uint(lo) >> 16);
}

// ============ W2 prep: [48][64] bf16 hi/lo (cols 40-47 zero) ============
__global__ void k_w2prep(const float* __restrict__ W2, short* __restrict__ hi,
                         short* __restrict__ lo){
  int i = blockIdx.x * 256 + threadIdx.x;    // 3072
  if (i >= 48 * 64) return;
  int c = i >> 6, k = i & 63;
  float v = (c < 40) ? W2[k * 40 + c] : 0.f;
  unsigned u = __float_as_uint(v);
  hi[c * 64 + k] = (short)(u >> 16);
  float l = v - bfhi_f(v);
  lo[c * 64 + k] = (short)(__float_as_uint(l) >> 16);
}

// ============ GEMM1 via MFMA (hi/lo split) + fused alpha1 + bf16 h1 write ============
__global__ __launch_bounds__(256) void k_gemm1_mfma(const float* __restrict__ x,
    const short* __restrict__ wt_hi, const short* __restrict__ wt_lo,
    const float* __restrict__ a1s, const float* __restrict__ a1d,
    unsigned short* __restrict__ h1b, float* __restrict__ as_, float* __restrict__ ad_, int N){
  int lane = threadIdx.x & 63;
  int wv   = threadIdx.x >> 6;
  int r0   = blockIdx.x * 64 + wv * 16;
  if (r0 >= N) return;
  int col16 = lane & 15;
  int kg    = lane >> 4;
  const float* xr = x + (size_t)min(r0 + col16, N - 1) * 256 + kg * 8;

  f32x4 acc[4];
  #pragma unroll
  for (int ct = 0; ct < 4; ct++) acc[ct] = (f32x4){0.f, 0.f, 0.f, 0.f};

  #pragma unroll 2
  for (int kt = 0; kt < 8; kt++){
    float4 v0 = *(const float4*)(xr + kt * 32);
    float4 v1 = *(const float4*)(xr + kt * 32 + 4);
    unsigned u[8] = {__float_as_uint(v0.x), __float_as_uint(v0.y), __float_as_uint(v0.z), __float_as_uint(v0.w),
                     __float_as_uint(v1.x), __float_as_uint(v1.y), __float_as_uint(v1.z), __float_as_uint(v1.w)};
    union { bf16x8 v; unsigned u[4]; } ahi, alo;
    #pragma unroll
    for (int j = 0; j < 4; j++)
      ahi.u[j] = __builtin_amdgcn_perm(u[2*j+1], u[2*j], 0x07060302);
    float lo[8];
    lo[0] = v0.x - bfhi_f(v0.x); lo[1] = v0.y - bfhi_f(v0.y);
    lo[2] = v0.z - bfhi_f(v0.z); lo[3] = v0.w - bfhi_f(v0.w);
    lo[4] = v1.x - bfhi_f(v1.x); lo[5] = v1.y - bfhi_f(v1.y);
    lo[6] = v1.z - bfhi_f(v1.z); lo[7] = v1.w - bfhi_f(v1.w);
    #pragma unroll
    for (int j = 0; j < 4; j++)
      alo.u[j] = __builtin_amdgcn_perm(__float_as_uint(lo[2*j+1]), __float_as_uint(lo[2*j]), 0x07060302);

    #pragma unroll
    for (int ct = 0; ct < 4; ct++){
      int wcol = ct * 16 + col16;
      const bf16x8 bhi = *(const bf16x8*)(wt_hi + wcol * 256 + kt * 32 + kg * 8);
      const bf16x8 blo = *(const bf16x8*)(wt_lo + wcol * 256 + kt * 32 + kg * 8);
      acc[ct] = __builtin_amdgcn_mfma_f32_16x16x32_bf16(ahi.v, bhi, acc[ct], 0, 0, 0);
      acc[ct] = __builtin_amdgcn_mfma_f32_16x16x32_bf16(ahi.v, blo, acc[ct], 0, 0, 0);
      acc[ct] = __builtin_amdgcn_mfma_f32_16x16x32_bf16(alo.v, bhi, acc[ct], 0, 0, 0);
    }
  }

  float cs[4], cd[4];
  #pragma unroll
  for (int ct = 0; ct < 4; ct++){ cs[ct] = a1s[ct * 16 + col16]; cd[ct] = a1d[ct * 16 + col16]; }
  #pragma unroll
  for (int r = 0; r < 4; r++){
    int rr = r0 + kg * 4 + r;
    bool ok = rr < N;
    #pragma unroll
    for (int ct = 0; ct < 4; ct++){
      float v = acc[ct][r];
      if (ok) h1b[(size_t)rr * 64 + ct * 16 + col16] = f2bf(v);
      float s = v * cs[ct];
      float t = v * cd[ct];
      s += __shfl_xor(s, 1, 64); s += __shfl_xor(s, 2, 64); s += __shfl_xor(s, 4, 64);
      t += __shfl_xor(t, 1, 64); t += __shfl_xor(t, 2, 64); t += __shfl_xor(t, 4, 64);
      if (ok && (col16 & 7) == 0){
        int head = ct * 2 + (col16 >> 3);
        as_[(size_t)rr * 8 + head] = s;
        ad_[(size_t)rr * 8 + head] = t;
      }
    }
  }
}

// ============ layer-1 per-dst gather: staged srcids, MLP-4 channel phase ============
__global__ __launch_bounds__(256) void k_gat1(const unsigned* __restrict__ off_, const unsigned* __restrict__ cur,
    const int* __restrict__ srcids, const float* __restrict__ as_, const float* __restrict__ ad_,
    const unsigned short* __restrict__ h1b, const float* __restrict__ b1,
    unsigned short* __restrict__ out1b, int N){
  int lane = threadIdx.x & 63;
  int wv   = threadIdx.x >> 6;
  int d    = blockIdx.x * 4 + wv;
  if (d >= N) return;
  __shared__ float lds_p[4][64 * 8];
  __shared__ int   lds_s[4][64];
  float* lp = lds_p[wv];
  int*   ls = lds_s[wv];
  unsigned beg = off_[d], fin = cur[d];

  int e8 = lane >> 3, h = lane & 7;                  // exp-phase layout
  int c0 = lane & 31, pe = lane >> 5, hh = c0 >> 2;  // channel-phase layout
  float adh = ad_[(size_t)d * 8 + h];
  float psacc = 0.f, accx = 0.f, accy = 0.f;

  for (unsigned base = beg; base < fin; base += 64){
    int nthis = (int)min(64u, fin - base);
    unsigned i = base + lane;
    ls[lane] = (i < fin) ? srcids[i] : 0;            // one coalesced stage
    asm volatile("s_waitcnt lgkmcnt(0)" ::: "memory");
    __builtin_amdgcn_sched_barrier(0);
    // exp phase: 8 edges x 8 heads per j-iter, 1 exp per lane, iterations independent
    for (int j = 0; j < nthis; j += 8){
      int eloc = j + e8;
      int s = ls[eloc];
      float p = 0.f;
      if (eloc < nthis) p = __expf(lrelu(as_[(size_t)s * 8 + h] + adh));
      lp[eloc * 8 + h] = p;
      psacc += p;
    }
    asm volatile("s_waitcnt lgkmcnt(0)" ::: "memory");
    __builtin_amdgcn_sched_barrier(0);
    // channel phase: 8 edges per iter, 4 independent gathers (MLP=4)
    for (int e = 0; e < nthis; e += 8){
      int e0 = e + pe, e1 = e + 2 + pe, e2 = e + 4 + pe, e3 = e + 6 + pe;
      float p0 = lp[e0 * 8 + hh], p1 = lp[e1 * 8 + hh];
      float p2 = lp[e2 * 8 + hh], p3 = lp[e3 * 8 + hh];
      int s0 = ls[e0], s1 = ls[e1], s2 = ls[e2], s3 = ls[e3];
      unsigned u0 = *(const unsigned*)(h1b + (size_t)s0 * 64 + c0 * 2);
      unsigned u1 = *(const unsigned*)(h1b + (size_t)s1 * 64 + c0 * 2);
      unsigned u2 = *(const unsigned*)(h1b + (size_t)s2 * 64 + c0 * 2);
      unsigned u3 = *(const unsigned*)(h1b + (size_t)s3 * 64 + c0 * 2);
      accx = fmaf(p0, __uint_as_float(u0 << 16), accx);
      accy = fmaf(p0, __uint_as_float(u0 & 0xFFFF0000u), accy);
      accx = fmaf(p1, __uint_as_float(u1 << 16), accx);
      accy = fmaf(p1, __uint_as_float(u1 & 0xFFFF0000u), accy);
      accx = fmaf(p2, __uint_as_float(u2 << 16), accx);
      accy = fmaf(p2, __uint_as_float(u2 & 0xFFFF0000u), accy);
      accx = fmaf(p3, __uint_as_float(u3 << 16), accx);
      accy = fmaf(p3, __uint_as_float(u3 & 0xFFFF0000u), accy);
    }
    asm volatile("" ::: "memory");
  }
  // per-head denominator: reduce over e8 groups (lanes with same h)
  float den = psacc;
  den += __shfl_xor(den, 8, 64);
  den += __shfl_xor(den, 16, 64);
  den += __shfl_xor(den, 32, 64);
  float mydenv = __shfl(den, hh, 64);          // lane hh holds head hh
  accx += __shfl_xor(accx, 32, 64);
  accy += __shfl_xor(accy, 32, 64);
  if (lane < 32){
    int ch = lane * 2;
    float v0 = accx / mydenv + b1[ch];
    float v1 = accy / mydenv + b1[ch + 1];
    ushort2 o;
    o.x = f2bf(v0 > 0.f ? v0 : 0.f);
    o.y = f2bf(v1 > 0.f ? v1 : 0.f);
    *(ushort2*)(out1b + (size_t)d * 64 + ch) = o;
  }
}

// ============ GEMM2 via MFMA (bf16 A, hi/lo B) + fused alpha2 ============
__global__ __launch_bounds__(256) void k_gemm2m(const unsigned short* __restrict__ out1b,
    const short* __restrict__ wt2_hi, const short* __restrict__ wt2_lo,
    const float* __restrict__ a2s, const float* __restrict__ a2d,
    unsigned short* __restrict__ h2b, float* __restrict__ as_, float* __restrict__ ad_, int N){
  int lane = threadIdx.x & 63;
  int wv   = threadIdx.x >> 6;
  int r0   = blockIdx.x * 64 + wv * 16;
  if (r0 >= N) return;
  int col16 = lane & 15;
  int kg    = lane >> 4;
  const unsigned short* ar = out1b + (size_t)min(r0 + col16, N - 1) * 64 + kg * 8;

  f32x4 acc[3];
  #pragma unroll
  for (int ct = 0; ct < 3; ct++) acc[ct] = (f32x4){0.f, 0.f, 0.f, 0.f};

  #pragma unroll
  for (int kt = 0; kt < 2; kt++){
    const bf16x8 a = *(const bf16x8*)(ar + kt * 32);
    #pragma unroll
    for (int ct = 0; ct < 3; ct++){
      int wcol = ct * 16 + col16;
      const bf16x8 bhi = *(const bf16x8*)(wt2_hi + wcol * 64 + kt * 32 + kg * 8);
      const bf16x8 blo = *(const bf16x8*)(wt2_lo + wcol * 64 + kt * 32 + kg * 8);
      acc[ct] = __builtin_amdgcn_mfma_f32_16x16x32_bf16(a, bhi, acc[ct], 0, 0, 0);
      acc[ct] = __builtin_amdgcn_mfma_f32_16x16x32_bf16(a, blo, acc[ct], 0, 0, 0);
    }
  }

  float cs[3], cd[3];
  #pragma unroll
  for (int ct = 0; ct < 3; ct++){
    int col = ct * 16 + col16;
    bool okc = col < 40;
    cs[ct] = okc ? a2s[col] : 0.f;
    cd[ct] = okc ? a2d[col] : 0.f;
  }
  #pragma unroll
  for (int r = 0; r < 4; r++){
    int rr = r0 + kg * 4 + r;
    bool ok = rr < N;
    float s = 0.f, t = 0.f;
    #pragma unroll
    for (int ct = 0; ct < 3; ct++){
      s = fmaf(acc[ct][r], cs[ct], s);
      t = fmaf(acc[ct][r], cd[ct], t);
      int col = ct * 16 + col16;
      if (ok && col < 40) h2b[(size_t)rr * 40 + col] = f2bf(acc[ct][r]);
    }
    s += __shfl_xor(s, 1, 64); s += __shfl_xor(s, 2, 64);
    s += __shfl_xor(s, 4, 64); s += __shfl_xor(s, 8, 64);
    t += __shfl_xor(t, 1, 64); t += __shfl_xor(t, 2, 64);
    t += __shfl_xor(t, 4, 64); t += __shfl_xor(t, 8, 64);
    if (ok && col16 == 0){ as_[rr] = s; ad_[rr] = t; }
  }
}

// ============ layer-2 per-dst gather (H=1, C=40), MLP-4 + fused bias+log_softmax ============
__global__ __launch_bounds__(256) void k_gat2(const unsigned* __restrict__ off_, const unsigned* __restrict__ cur,
    const int* __restrict__ srcids, const float* __restrict__ as_, const float* __restrict__ ad_,
    const unsigned short* __restrict__ h2b, const float* __restrict__ b2, float* __restrict__ out, int N){
  int lane = threadIdx.x & 63;
  int wv   = threadIdx.x >> 6;
  int d    = blockIdx.x * 4 + wv;
  if (d >= N) return;
  __shared__ float lds_p[4][64];
  __shared__ int   lds_s[4][64];
  float* lp = lds_p[wv];
  int*   ls = lds_s[wv];
  unsigned beg = off_[d], fin = cur[d];
  float add = ad_[d];

  int c0 = lane & 31;
  int pe = lane >> 5;
  int idx = c0 < 20 ? c0 : 19;
  float ps = 0.f, accx = 0.f, accy = 0.f;

  for (unsigned base = beg; base < fin; base += 64){
    unsigned i = base + lane;
    int nthis = (int)min(64u, fin - base);
    if (i < fin){
      int s = srcids[i];
      float p = __expf(lrelu(as_[s] + add));
      ps += p; ls[lane] = s; lp[lane] = p;
    } else { ls[lane] = 0; lp[lane] = 0.f; }
    asm volatile("s_waitcnt lgkmcnt(0)" ::: "memory");
    __builtin_amdgcn_sched_barrier(0);
    for (int e = 0; e < nthis; e += 8){
      int e0 = e + pe, e1 = e + 2 + pe, e2 = e + 4 + pe, e3 = e + 6 + pe;
      float p0 = lp[e0], p1 = lp[e1], p2 = lp[e2], p3 = lp[e3];
      int s0 = ls[e0], s1 = ls[e1], s2 = ls[e2], s3 = ls[e3];
      unsigned u0 = *(const unsigned*)(h2b + (size_t)s0 * 40 + idx * 2);
      unsigned u1 = *(const unsigned*)(h2b + (size_t)s1 * 40 + idx * 2);
      unsigned u2 = *(const unsigned*)(h2b + (size_t)s2 * 40 + idx * 2);
      unsigned u3 = *(const unsigned*)(h2b + (size_t)s3 * 40 + idx * 2);
      accx = fmaf(p0, __uint_as_float(u0 << 16), accx);
      accy = fmaf(p0, __uint_as_float(u0 & 0xFFFF0000u), accy);
      accx = fmaf(p1, __uint_as_float(u1 << 16), accx);
      accy = fmaf(p1, __uint_as_float(u1 & 0xFFFF0000u), accy);
      accx = fmaf(p2, __uint_as_float(u2 << 16), accx);
      accy = fmaf(p2, __uint_as_float(u2 & 0xFFFF0000u), accy);
      accx = fmaf(p3, __uint_as_float(u3 << 16), accx);
      accy = fmaf(p3, __uint_as_float(u3 & 0xFFFF0000u), accy);
    }
    asm volatile("" ::: "memory");
  }
  ps = wred_sum(ps);
  accx += __shfl_xor(accx, 32, 64);
  accy += __shfl_xor(accy, 32, 64);

  // fused bias + log_softmax over 40 channels (lanes' halves are identical)
  float v0 = accx / ps + b2[idx * 2];
  float v1 = accy / ps + b2[idx * 2 + 1];
  bool act = (c0 < 20);
  float mx = act ? fmaxf(v0, v1) : -INFINITY;
  #pragma unroll
  for (int o = 16; o; o >>= 1) mx = fmaxf(mx, __shfl_xor(mx, o, 64));
  float exs = act ? (__expf(v0 - mx) + __expf(v1 - mx)) : 0.f;
  #pragma unroll
  for (int o = 16; o; o >>= 1) exs += __shfl_xor(exs, o, 64);
  float lse = mx + logf(exs);
  if (lane < 20){
    float2 o2; o2.x = v0 - lse; o2.y = v1 - lse;
    *(float2*)(out + (size_t)d * 40 + lane * 2) = o2;
  }
}

extern "C" void kernel_launch(void* const* d_in, const int* in_sizes, int n_in,
                              void* d_out, int out_size, void* d_ws, size_t ws_size,
                              hipStream_t stream){
  const float* x   = (const float*)d_in[0];
  const int*   ei  = (const int*)d_in[1];
  const float* W1  = (const float*)d_in[2];
  const float* a1s = (const float*)d_in[3];
  const float* a1d = (const float*)d_in[4];
  const float* b1  = (const float*)d_in[5];
  const float* W2  = (const float*)d_in[6];
  const float* a2s = (const float*)d_in[7];
  const float* a2d = (const float*)d_in[8];
  const float* b2  = (const float*)d_in[9];
  float* out = (float*)d_out;

  const int N = in_sizes[0] / 256;
  const int E = in_sizes[1] / 2;
  const int tot = E + N;
  const int nb  = (N + 255) >> 8;

  float* ws = (float*)d_ws;
  size_t o = 0;
  float* as1  = ws + o; o += (size_t)N * 8;
  float* ad1  = ws + o; o += (size_t)N * 8;
  unsigned short* out1b = (unsigned short*)(ws + o); o += (size_t)N * 32;  // aliases `staged`
  unsigned short* h1b   = (unsigned short*)(ws + o); o += (size_t)N * 32;
  unsigned short* h2b   = (unsigned short*)(ws + o); o += (size_t)N * 20;
  unsigned* off_ = (unsigned*)(ws + o); o += (size_t)N;
  unsigned* cur  = (unsigned*)(ws + o); o += (size_t)N;
  int* srcids    = (int*)(ws + o);      o += (size_t)tot;
  short* wt_hi   = (short*)(ws + o);    o += 8192;   // 16384 bf16
  short* wt_lo   = (short*)(ws + o);    o += 8192;
  short* wt2_hi  = (short*)(ws + o);    o += 1536;   // 3072 bf16 (48x64)
  short* wt2_lo  = (short*)(ws + o);    o += 1536;
  unsigned* bcnt  = (unsigned*)(ws + o); o += nb;
  unsigned* bbase = (unsigned*)(ws + o); o += nb + 1;
  unsigned* bcur  = (unsigned*)(ws + o); o += nb;
  unsigned* staged = (unsigned*)out1b;
  float* as2 = as1;
  float* ad2 = ad1;

  const int cb = (tot + 8191) / 8192;

  hipMemsetAsync(bcnt, 0, sizeof(unsigned) * (size_t)nb, stream);

  // bucketed CSR build
  k_bincnt <<<cb, 256, 0, stream>>>(ei, E, N, nb, bcnt);
  k_bscan  <<<1, 512, 0, stream>>>(bcnt, bbase, bcur, nb, tot);
  k_binscat<<<cb, 256, 0, stream>>>(ei, E, N, nb, bcur, staged);
  k_csr    <<<nb, 256, 0, stream>>>(bbase, staged, N, off_, cur, srcids);

  // weight prep
  k_wprep <<<64, 256, 0, stream>>>(W1, wt_hi, wt_lo);
  k_w2prep<<<12, 256, 0, stream>>>(W2, wt2_hi, wt2_lo);

  // layer 1
  k_gemm1_mfma<<<(N + 63) / 64, 256, 0, stream>>>(x, wt_hi, wt_lo, a1s, a1d, h1b, as1, ad1, N);
  k_gat1 <<<(N + 3) / 4, 256, 0, stream>>>(off_, cur, srcids, as1, ad1, h1b, b1, out1b, N);

  // layer 2
  k_gemm2m<<<(N + 63) / 64, 256, 0, stream>>>(out1b, wt2_hi, wt2_lo, a2s, a2d, h2b, as2, ad2, N);
  k_gat2  <<<(N + 3) / 4, 256, 0, stream>>>(off_, cur, srcids, as2, ad2, h2b, b2, out, N);
}

// Round 9
// 266.459 us; speedup vs baseline: 40.6198x; 1.0031x over previous
//
#include <hip/hip_runtime.h>
#include <math.h>

#define NEG_SLOPE 0.2f
__device__ __forceinline__ float lrelu(float x){ return x >= 0.f ? x : NEG_SLOPE * x; }

typedef __attribute__((ext_vector_type(8))) short bf16x8;
typedef __attribute__((ext_vector_type(4))) float f32x4;

__device__ __forceinline__ float wred_sum(float v){
  #pragma unroll
  for (int o = 32; o; o >>= 1) v += __shfl_xor(v, o, 64);
  return v;
}

__device__ __forceinline__ float bfhi_f(float f){
  return __uint_as_float(__float_as_uint(f) & 0xFFFF0000u);
}
// fp32 -> bf16 RTNE
__device__ __forceinline__ unsigned short f2bf(float f){
  unsigned u = __float_as_uint(f);
  unsigned r = u + 0x7FFFu + ((u >> 16) & 1u);
  return (unsigned short)(r >> 16);
}

// ================= bucketed CSR build =================
__global__ __launch_bounds__(256) void k_bincnt(const int* __restrict__ ei, int E, int N, int nb,
                                                unsigned* __restrict__ bcnt){
  __shared__ unsigned h[512];
  const int tot = E + N;
  for (int i = threadIdx.x; i < nb; i += 256) h[i] = 0;
  __syncthreads();
  int base = blockIdx.x * 8192;
  #pragma unroll 4
  for (int j = 0; j < 32; j++){
    int e = base + threadIdx.x + j * 256;
    if (e < tot){
      unsigned d = (e < E) ? (unsigned)ei[E + e] : (unsigned)(e - E);
      atomicAdd(&h[d >> 8], 1u);
    }
  }
  __syncthreads();
  for (int i = threadIdx.x; i < nb; i += 256)
    if (h[i]) atomicAdd(&bcnt[i], h[i]);
}

__global__ void k_bscan(const unsigned* __restrict__ bcnt, unsigned* __restrict__ bbase,
                        unsigned* __restrict__ bcur, int nb, int tot){
  __shared__ unsigned s[512];
  int t = threadIdx.x;
  unsigned v = (t < nb) ? bcnt[t] : 0u;
  s[t] = v; __syncthreads();
  for (int off = 1; off < 512; off <<= 1){
    unsigned x = (t >= off) ? s[t - off] : 0u; __syncthreads();
    s[t] += x; __syncthreads();
  }
  if (t < nb){ unsigned b = s[t] - v; bbase[t] = b; bcur[t] = b; }
  if (t == 0) bbase[nb] = (unsigned)tot;
}

__global__ __launch_bounds__(256) void k_binscat(const int* __restrict__ ei, int E, int N, int nb,
    unsigned* __restrict__ bcur, unsigned* __restrict__ staged){
  __shared__ unsigned sd[8192];
  __shared__ unsigned hist[512];
  __shared__ unsigned runb[512];
  const int tot = E + N;
  for (int i = threadIdx.x; i < nb; i += 256) hist[i] = 0;
  __syncthreads();
  int base = blockIdx.x * 8192;
  #pragma unroll 4
  for (int j = 0; j < 32; j++){
    int idx = threadIdx.x + j * 256;
    int e = base + idx;
    unsigned d = 0xFFFFFFFFu;
    if (e < tot) d = (e < E) ? (unsigned)ei[E + e] : (unsigned)(e - E);
    sd[idx] = d;
    if (d != 0xFFFFFFFFu) atomicAdd(&hist[d >> 8], 1u);
  }
  __syncthreads();
  for (int i = threadIdx.x; i < nb; i += 256){
    unsigned c = hist[i];
    runb[i] = c ? atomicAdd(&bcur[i], c) : 0u;
    hist[i] = 0;
  }
  __syncthreads();
  #pragma unroll 4
  for (int j = 0; j < 32; j++){
    int idx = threadIdx.x + j * 256;
    unsigned d = sd[idx];
    if (d == 0xFFFFFFFFu) continue;
    int e = base + idx;
    unsigned s = (e < E) ? (unsigned)ei[e] : d;
    unsigned b = d >> 8;
    unsigned pos = runb[b] + atomicAdd(&hist[b], 1u);
    staged[pos] = s | ((d & 255u) << 20);
  }
}

__global__ __launch_bounds__(256) void k_csr(const unsigned* __restrict__ bbase,
    const unsigned* __restrict__ staged, int N,
    unsigned* __restrict__ off_, unsigned* __restrict__ cur, int* __restrict__ srcids){
  __shared__ unsigned cnt[256], scn[256], cnt2[256];
  int b = blockIdx.x, t = threadIdx.x;
  unsigned beg = bbase[b], end = bbase[b + 1];
  cnt[t] = 0; cnt2[t] = 0;
  __syncthreads();
  for (unsigned i = beg + t; i < end; i += 256)
    atomicAdd(&cnt[staged[i] >> 20], 1u);
  __syncthreads();
  unsigned v = cnt[t];
  scn[t] = v; __syncthreads();
  for (int off = 1; off < 256; off <<= 1){
    unsigned x = (t >= off) ? scn[t - off] : 0u; __syncthreads();
    scn[t] += x; __syncthreads();
  }
  unsigned ex = scn[t] - v;
  int d = b * 256 + t;
  if (d < N){ off_[d] = beg + ex; cur[d] = beg + ex + v; }
  cnt[t] = ex;
  __syncthreads();
  for (unsigned i = beg + t; i < end; i += 256){
    unsigned u = staged[i];
    unsigned dl = u >> 20;
    unsigned pos = beg + cnt[dl] + atomicAdd(&cnt2[dl], 1u);
    srcids[pos] = (int)(u & 0xFFFFFu);
  }
}

// ============ W1 prep: Wt_hi/Wt_lo[64][256] bf16 ============
__global__ void k_wprep(const float* __restrict__ W, short* __restrict__ wt_hi,
                        short* __restrict__ wt_lo){
  int i = blockIdx.x * 256 + threadIdx.x;    // 16384
  int k = i >> 6, c = i & 63;
  float v = W[i];
  unsigned u = __float_as_uint(v);
  wt_hi[c * 256 + k] = (short)(u >> 16);
  float lo = v - bfhi_f(v);
  wt_lo[c * 256 + k] = (short)(__float_as_uint(lo) >> 16);
}

// ============ W2 prep: [48][64] bf16 hi/lo (cols 40-47 zero) ============
__global__ void k_w2prep(const float* __restrict__ W2, short* __restrict__ hi,
                         short* __restrict__ lo){
  int i = blockIdx.x * 256 + threadIdx.x;    // 3072
  if (i >= 48 * 64) return;
  int c = i >> 6, k = i & 63;
  float v = (c < 40) ? W2[k * 40 + c] : 0.f;
  unsigned u = __float_as_uint(v);
  hi[c * 64 + k] = (short)(u >> 16);
  float l = v - bfhi_f(v);
  lo[c * 64 + k] = (short)(__float_as_uint(l) >> 16);
}

// ============ GEMM1 via MFMA (hi/lo split), load-all-then-compute K-loop ============
__global__ __launch_bounds__(256) void k_gemm1_mfma(const float* __restrict__ x,
    const short* __restrict__ wt_hi, const short* __restrict__ wt_lo,
    const float* __restrict__ a1s, const float* __restrict__ a1d,
    unsigned short* __restrict__ h1b, float* __restrict__ as_, float* __restrict__ ad_, int N){
  int lane = threadIdx.x & 63;
  int wv   = threadIdx.x >> 6;
  int r0   = blockIdx.x * 64 + wv * 16;
  if (r0 >= N) return;
  int col16 = lane & 15;
  int kg    = lane >> 4;
  const float4* xr = (const float4*)(x + (size_t)min(r0 + col16, N - 1) * 256 + kg * 8);

  // hoist the wave's full 256-B row fragment into registers (16 independent loads, MLP=16)
  float4 xv[16];
  #pragma unroll
  for (int kt = 0; kt < 8; kt++){
    xv[2 * kt]     = xr[kt * 8];
    xv[2 * kt + 1] = xr[kt * 8 + 1];
  }

  f32x4 acc[4];
  #pragma unroll
  for (int ct = 0; ct < 4; ct++) acc[ct] = (f32x4){0.f, 0.f, 0.f, 0.f};

  #pragma unroll
  for (int kt = 0; kt < 8; kt++){
    float4 v0 = xv[2 * kt], v1 = xv[2 * kt + 1];
    unsigned u[8] = {__float_as_uint(v0.x), __float_as_uint(v0.y), __float_as_uint(v0.z), __float_as_uint(v0.w),
                     __float_as_uint(v1.x), __float_as_uint(v1.y), __float_as_uint(v1.z), __float_as_uint(v1.w)};
    union { bf16x8 v; unsigned u[4]; } ahi, alo;
    #pragma unroll
    for (int j = 0; j < 4; j++)
      ahi.u[j] = __builtin_amdgcn_perm(u[2*j+1], u[2*j], 0x07060302);
    float lo[8];
    lo[0] = v0.x - bfhi_f(v0.x); lo[1] = v0.y - bfhi_f(v0.y);
    lo[2] = v0.z - bfhi_f(v0.z); lo[3] = v0.w - bfhi_f(v0.w);
    lo[4] = v1.x - bfhi_f(v1.x); lo[5] = v1.y - bfhi_f(v1.y);
    lo[6] = v1.z - bfhi_f(v1.z); lo[7] = v1.w - bfhi_f(v1.w);
    #pragma unroll
    for (int j = 0; j < 4; j++)
      alo.u[j] = __builtin_amdgcn_perm(__float_as_uint(lo[2*j+1]), __float_as_uint(lo[2*j]), 0x07060302);

    #pragma unroll
    for (int ct = 0; ct < 4; ct++){
      int wcol = ct * 16 + col16;
      const bf16x8 bhi = *(const bf16x8*)(wt_hi + wcol * 256 + kt * 32 + kg * 8);
      const bf16x8 blo = *(const bf16x8*)(wt_lo + wcol * 256 + kt * 32 + kg * 8);
      acc[ct] = __builtin_amdgcn_mfma_f32_16x16x32_bf16(ahi.v, bhi, acc[ct], 0, 0, 0);
      acc[ct] = __builtin_amdgcn_mfma_f32_16x16x32_bf16(ahi.v, blo, acc[ct], 0, 0, 0);
      acc[ct] = __builtin_amdgcn_mfma_f32_16x16x32_bf16(alo.v, bhi, acc[ct], 0, 0, 0);
    }
  }

  float cs[4], cd[4];
  #pragma unroll
  for (int ct = 0; ct < 4; ct++){ cs[ct] = a1s[ct * 16 + col16]; cd[ct] = a1d[ct * 16 + col16]; }
  #pragma unroll
  for (int r = 0; r < 4; r++){
    int rr = r0 + kg * 4 + r;
    bool ok = rr < N;
    #pragma unroll
    for (int ct = 0; ct < 4; ct++){
      float v = acc[ct][r];
      if (ok) h1b[(size_t)rr * 64 + ct * 16 + col16] = f2bf(v);
      float s = v * cs[ct];
      float t = v * cd[ct];
      s += __shfl_xor(s, 1, 64); s += __shfl_xor(s, 2, 64); s += __shfl_xor(s, 4, 64);
      t += __shfl_xor(t, 1, 64); t += __shfl_xor(t, 2, 64); t += __shfl_xor(t, 4, 64);
      if (ok && (col16 & 7) == 0){
        int head = ct * 2 + (col16 >> 3);
        as_[(size_t)rr * 8 + head] = s;
        ad_[(size_t)rr * 8 + head] = t;
      }
    }
  }
}

// ============ layer-1 per-dst gather: staged srcids, MLP-4 channel phase ============
__global__ __launch_bounds__(256) void k_gat1(const unsigned* __restrict__ off_, const unsigned* __restrict__ cur,
    const int* __restrict__ srcids, const float* __restrict__ as_, const float* __restrict__ ad_,
    const unsigned short* __restrict__ h1b, const float* __restrict__ b1,
    unsigned short* __restrict__ out1b, int N){
  int lane = threadIdx.x & 63;
  int wv   = threadIdx.x >> 6;
  int d    = blockIdx.x * 4 + wv;
  if (d >= N) return;
  __shared__ float lds_p[4][64 * 8];
  __shared__ int   lds_s[4][64];
  float* lp = lds_p[wv];
  int*   ls = lds_s[wv];
  unsigned beg = off_[d], fin = cur[d];

  int e8 = lane >> 3, h = lane & 7;                  // exp-phase layout
  int c0 = lane & 31, pe = lane >> 5, hh = c0 >> 2;  // channel-phase layout
  float adh = ad_[(size_t)d * 8 + h];
  float psacc = 0.f, accx = 0.f, accy = 0.f;

  for (unsigned base = beg; base < fin; base += 64){
    int nthis = (int)min(64u, fin - base);
    unsigned i = base + lane;
    ls[lane] = (i < fin) ? srcids[i] : 0;            // one coalesced stage
    asm volatile("s_waitcnt lgkmcnt(0)" ::: "memory");
    __builtin_amdgcn_sched_barrier(0);
    // exp phase: 8 edges x 8 heads per j-iter, 1 exp per lane, iterations independent
    for (int j = 0; j < nthis; j += 8){
      int eloc = j + e8;
      int s = ls[eloc];
      float p = 0.f;
      if (eloc < nthis) p = __expf(lrelu(as_[(size_t)s * 8 + h] + adh));
      lp[eloc * 8 + h] = p;
      psacc += p;
    }
    asm volatile("s_waitcnt lgkmcnt(0)" ::: "memory");
    __builtin_amdgcn_sched_barrier(0);
    // channel phase: 8 edges per iter, 4 independent gathers (MLP=4)
    for (int e = 0; e < nthis; e += 8){
      int e0 = e + pe, e1 = e + 2 + pe, e2 = e + 4 + pe, e3 = e + 6 + pe;
      float p0 = lp[e0 * 8 + hh], p1 = lp[e1 * 8 + hh];
      float p2 = lp[e2 * 8 + hh], p3 = lp[e3 * 8 + hh];
      int s0 = ls[e0], s1 = ls[e1], s2 = ls[e2], s3 = ls[e3];
      unsigned u0 = *(const unsigned*)(h1b + (size_t)s0 * 64 + c0 * 2);
      unsigned u1 = *(const unsigned*)(h1b + (size_t)s1 * 64 + c0 * 2);
      unsigned u2 = *(const unsigned*)(h1b + (size_t)s2 * 64 + c0 * 2);
      unsigned u3 = *(const unsigned*)(h1b + (size_t)s3 * 64 + c0 * 2);
      accx = fmaf(p0, __uint_as_float(u0 << 16), accx);
      accy = fmaf(p0, __uint_as_float(u0 & 0xFFFF0000u), accy);
      accx = fmaf(p1, __uint_as_float(u1 << 16), accx);
      accy = fmaf(p1, __uint_as_float(u1 & 0xFFFF0000u), accy);
      accx = fmaf(p2, __uint_as_float(u2 << 16), accx);
      accy = fmaf(p2, __uint_as_float(u2 & 0xFFFF0000u), accy);
      accx = fmaf(p3, __uint_as_float(u3 << 16), accx);
      accy = fmaf(p3, __uint_as_float(u3 & 0xFFFF0000u), accy);
    }
    asm volatile("" ::: "memory");
  }
  // per-head denominator: reduce over e8 groups (lanes with same h)
  float den = psacc;
  den += __shfl_xor(den, 8, 64);
  den += __shfl_xor(den, 16, 64);
  den += __shfl_xor(den, 32, 64);
  float mydenv = __shfl(den, hh, 64);          // lane hh holds head hh
  accx += __shfl_xor(accx, 32, 64);
  accy += __shfl_xor(accy, 32, 64);
  if (lane < 32){
    int ch = lane * 2;
    float v0 = accx / mydenv + b1[ch];
    float v1 = accy / mydenv + b1[ch + 1];
    ushort2 o;
    o.x = f2bf(v0 > 0.f ? v0 : 0.f);
    o.y = f2bf(v1 > 0.f ? v1 : 0.f);
    *(ushort2*)(out1b + (size_t)d * 64 + ch) = o;
  }
}

// ============ GEMM2 via MFMA (bf16 A, hi/lo B) + fused alpha2 ============
__global__ __launch_bounds__(256) void k_gemm2m(const unsigned short* __restrict__ out1b,
    const short* __restrict__ wt2_hi, const short* __restrict__ wt2_lo,
    const float* __restrict__ a2s, const float* __restrict__ a2d,
    unsigned short* __restrict__ h2b, float* __restrict__ as_, float* __restrict__ ad_, int N){
  int lane = threadIdx.x & 63;
  int wv   = threadIdx.x >> 6;
  int r0   = blockIdx.x * 64 + wv * 16;
  if (r0 >= N) return;
  int col16 = lane & 15;
  int kg    = lane >> 4;
  const unsigned short* ar = out1b + (size_t)min(r0 + col16, N - 1) * 64 + kg * 8;

  f32x4 acc[3];
  #pragma unroll
  for (int ct = 0; ct < 3; ct++) acc[ct] = (f32x4){0.f, 0.f, 0.f, 0.f};

  #pragma unroll
  for (int kt = 0; kt < 2; kt++){
    const bf16x8 a = *(const bf16x8*)(ar + kt * 32);
    #pragma unroll
    for (int ct = 0; ct < 3; ct++){
      int wcol = ct * 16 + col16;
      const bf16x8 bhi = *(const bf16x8*)(wt2_hi + wcol * 64 + kt * 32 + kg * 8);
      const bf16x8 blo = *(const bf16x8*)(wt2_lo + wcol * 64 + kt * 32 + kg * 8);
      acc[ct] = __builtin_amdgcn_mfma_f32_16x16x32_bf16(a, bhi, acc[ct], 0, 0, 0);
      acc[ct] = __builtin_amdgcn_mfma_f32_16x16x32_bf16(a, blo, acc[ct], 0, 0, 0);
    }
  }

  float cs[3], cd[3];
  #pragma unroll
  for (int ct = 0; ct < 3; ct++){
    int col = ct * 16 + col16;
    bool okc = col < 40;
    cs[ct] = okc ? a2s[col] : 0.f;
    cd[ct] = okc ? a2d[col] : 0.f;
  }
  #pragma unroll
  for (int r = 0; r < 4; r++){
    int rr = r0 + kg * 4 + r;
    bool ok = rr < N;
    float s = 0.f, t = 0.f;
    #pragma unroll
    for (int ct = 0; ct < 3; ct++){
      s = fmaf(acc[ct][r], cs[ct], s);
      t = fmaf(acc[ct][r], cd[ct], t);
      int col = ct * 16 + col16;
      if (ok && col < 40) h2b[(size_t)rr * 40 + col] = f2bf(acc[ct][r]);
    }
    s += __shfl_xor(s, 1, 64); s += __shfl_xor(s, 2, 64);
    s += __shfl_xor(s, 4, 64); s += __shfl_xor(s, 8, 64);
    t += __shfl_xor(t, 1, 64); t += __shfl_xor(t, 2, 64);
    t += __shfl_xor(t, 4, 64); t += __shfl_xor(t, 8, 64);
    if (ok && col16 == 0){ as_[rr] = s; ad_[rr] = t; }
  }
}

// ============ layer-2 per-dst gather (H=1, C=40), MLP-4 + fused bias+log_softmax ============
__global__ __launch_bounds__(256) void k_gat2(const unsigned* __restrict__ off_, const unsigned* __restrict__ cur,
    const int* __restrict__ srcids, const float* __restrict__ as_, const float* __restrict__ ad_,
    const unsigned short* __restrict__ h2b, const float* __restrict__ b2, float* __restrict__ out, int N){
  int lane = threadIdx.x & 63;
  int wv   = threadIdx.x >> 6;
  int d    = blockIdx.x * 4 + wv;
  if (d >= N) return;
  __shared__ float lds_p[4][64];
  __shared__ int   lds_s[4][64];
  float* lp = lds_p[wv];
  int*   ls = lds_s[wv];
  unsigned beg = off_[d], fin = cur[d];
  float add = ad_[d];

  int c0 = lane & 31;
  int pe = lane >> 5;
  int idx = c0 < 20 ? c0 : 19;
  float ps = 0.f, accx = 0.f, accy = 0.f;

  for (unsigned base = beg; base < fin; base += 64){
    unsigned i = base + lane;
    int nthis = (int)min(64u, fin - base);
    if (i < fin){
      int s = srcids[i];
      float p = __expf(lrelu(as_[s] + add));
      ps += p; ls[lane] = s; lp[lane] = p;
    } else { ls[lane] = 0; lp[lane] = 0.f; }
    asm volatile("s_waitcnt lgkmcnt(0)" ::: "memory");
    __builtin_amdgcn_sched_barrier(0);
    for (int e = 0; e < nthis; e += 8){
      int e0 = e + pe, e1 = e + 2 + pe, e2 = e + 4 + pe, e3 = e + 6 + pe;
      float p0 = lp[e0], p1 = lp[e1], p2 = lp[e2], p3 = lp[e3];
      int s0 = ls[e0], s1 = ls[e1], s2 = ls[e2], s3 = ls[e3];
      unsigned u0 = *(const unsigned*)(h2b + (size_t)s0 * 40 + idx * 2);
      unsigned u1 = *(const unsigned*)(h2b + (size_t)s1 * 40 + idx * 2);
      unsigned u2 = *(const unsigned*)(h2b + (size_t)s2 * 40 + idx * 2);
      unsigned u3 = *(const unsigned*)(h2b + (size_t)s3 * 40 + idx * 2);
      accx = fmaf(p0, __uint_as_float(u0 << 16), accx);
      accy = fmaf(p0, __uint_as_float(u0 & 0xFFFF0000u), accy);
      accx = fmaf(p1, __uint_as_float(u1 << 16), accx);
      accy = fmaf(p1, __uint_as_float(u1 & 0xFFFF0000u), accy);
      accx = fmaf(p2, __uint_as_float(u2 << 16), accx);
      accy = fmaf(p2, __uint_as_float(u2 & 0xFFFF0000u), accy);
      accx = fmaf(p3, __uint_as_float(u3 << 16), accx);
      accy = fmaf(p3, __uint_as_float(u3 & 0xFFFF0000u), accy);
    }
    asm volatile("" ::: "memory");
  }
  ps = wred_sum(ps);
  accx += __shfl_xor(accx, 32, 64);
  accy += __shfl_xor(accy, 32, 64);

  // fused bias + log_softmax over 40 channels (lanes' halves are identical)
  float v0 = accx / ps + b2[idx * 2];
  float v1 = accy / ps + b2[idx * 2 + 1];
  bool act = (c0 < 20);
  float mx = act ? fmaxf(v0, v1) : -INFINITY;
  #pragma unroll
  for (int o = 16; o; o >>= 1) mx = fmaxf(mx, __shfl_xor(mx, o, 64));
  float exs = act ? (__expf(v0 - mx) + __expf(v1 - mx)) : 0.f;
  #pragma unroll
  for (int o = 16; o; o >>= 1) exs += __shfl_xor(exs, o, 64);
  float lse = mx + logf(exs);
  if (lane < 20){
    float2 o2; o2.x = v0 - lse; o2.y = v1 - lse;
    *(float2*)(out + (size_t)d * 40 + lane * 2) = o2;
  }
}

extern "C" void kernel_launch(void* const* d_in, const int* in_sizes, int n_in,
                              void* d_out, int out_size, void* d_ws, size_t ws_size,
                              hipStream_t stream){
  const float* x   = (const float*)d_in[0];
  const int*   ei  = (const int*)d_in[1];
  const float* W1  = (const float*)d_in[2];
  const float* a1s = (const float*)d_in[3];
  const float* a1d = (const float*)d_in[4];
  const float* b1  = (const float*)d_in[5];
  const float* W2  = (const float*)d_in[6];
  const float* a2s = (const float*)d_in[7];
  const float* a2d = (const float*)d_in[8];
  const float* b2  = (const float*)d_in[9];
  float* out = (float*)d_out;

  const int N = in_sizes[0] / 256;
  const int E = in_sizes[1] / 2;
  const int tot = E + N;
  const int nb  = (N + 255) >> 8;

  float* ws = (float*)d_ws;
  size_t o = 0;
  float* as1  = ws + o; o += (size_t)N * 8;
  float* ad1  = ws + o; o += (size_t)N * 8;
  unsigned short* out1b = (unsigned short*)(ws + o); o += (size_t)N * 32;  // aliases `staged`
  unsigned short* h1b   = (unsigned short*)(ws + o); o += (size_t)N * 32;
  unsigned short* h2b   = (unsigned short*)(ws + o); o += (size_t)N * 20;
  unsigned* off_ = (unsigned*)(ws + o); o += (size_t)N;
  unsigned* cur  = (unsigned*)(ws + o); o += (size_t)N;
  int* srcids    = (int*)(ws + o);      o += (size_t)tot;
  short* wt_hi   = (short*)(ws + o);    o += 8192;   // 16384 bf16
  short* wt_lo   = (short*)(ws + o);    o += 8192;
  short* wt2_hi  = (short*)(ws + o);    o += 1536;   // 3072 bf16 (48x64)
  short* wt2_lo  = (short*)(ws + o);    o += 1536;
  unsigned* bcnt  = (unsigned*)(ws + o); o += nb;
  unsigned* bbase = (unsigned*)(ws + o); o += nb + 1;
  unsigned* bcur  = (unsigned*)(ws + o); o += nb;
  unsigned* staged = (unsigned*)out1b;
  float* as2 = as1;
  float* ad2 = ad1;

  const int cb = (tot + 8191) / 8192;

  hipMemsetAsync(bcnt, 0, sizeof(unsigned) * (size_t)nb, stream);

  // bucketed CSR build
  k_bincnt <<<cb, 256, 0, stream>>>(ei, E, N, nb, bcnt);
  k_bscan  <<<1, 512, 0, stream>>>(bcnt, bbase, bcur, nb, tot);
  k_binscat<<<cb, 256, 0, stream>>>(ei, E, N, nb, bcur, staged);
  k_csr    <<<nb, 256, 0, stream>>>(bbase, staged, N, off_, cur, srcids);

  // weight prep
  k_wprep <<<64, 256, 0, stream>>>(W1, wt_hi, wt_lo);
  k_w2prep<<<12, 256, 0, stream>>>(W2, wt2_hi, wt2_lo);

  // layer 1
  k_gemm1_mfma<<<(N + 63) / 64, 256, 0, stream>>>(x, wt_hi, wt_lo, a1s, a1d, h1b, as1, ad1, N);
  k_gat1 <<<(N + 3) / 4, 256, 0, stream>>>(off_, cur, srcids, as1, ad1, h1b, b1, out1b, N);

  // layer 2
  k_gemm2m<<<(N + 63) / 64, 256, 0, stream>>>(out1b, wt2_hi, wt2_lo, a2s, a2d, h2b, as2, ad2, N);
  k_gat2  <<<(N + 3) / 4, 256, 0, stream>>>(off_, cur, srcids, as2, ad2, h2b, b2, out, N);
}

// Round 10
// 261.824 us; speedup vs baseline: 41.3389x; 1.0177x over previous
//
#include <hip/hip_runtime.h>
#include <math.h>

#define NEG_SLOPE 0.2f
__device__ __forceinline__ float lrelu(float x){ return x >= 0.f ? x : NEG_SLOPE * x; }

typedef __attribute__((ext_vector_type(8))) short bf16x8;
typedef __attribute__((ext_vector_type(4))) float f32x4;

__device__ __forceinline__ float wred_sum(float v){
  #pragma unroll
  for (int o = 32; o; o >>= 1) v += __shfl_xor(v, o, 64);
  return v;
}

__device__ __forceinline__ float bfhi_f(float f){
  return __uint_as_float(__float_as_uint(f) & 0xFFFF0000u);
}
// fp32 -> bf16 RTNE
__device__ __forceinline__ unsigned short f2bf(float f){
  unsigned u = __float_as_uint(f);
  unsigned r = u + 0x7FFFu + ((u >> 16) & 1u);
  return (unsigned short)(r >> 16);
}

// ================= bucketed CSR build =================
__global__ __launch_bounds__(256) void k_bincnt(const int* __restrict__ ei, int E, int N, int nb,
                                                unsigned* __restrict__ bcnt){
  __shared__ unsigned h[512];
  const int tot = E + N;
  for (int i = threadIdx.x; i < nb; i += 256) h[i] = 0;
  __syncthreads();
  int base = blockIdx.x * 8192;
  #pragma unroll 4
  for (int j = 0; j < 32; j++){
    int e = base + threadIdx.x + j * 256;
    if (e < tot){
      unsigned d = (e < E) ? (unsigned)ei[E + e] : (unsigned)(e - E);
      atomicAdd(&h[d >> 8], 1u);
    }
  }
  __syncthreads();
  for (int i = threadIdx.x; i < nb; i += 256)
    if (h[i]) atomicAdd(&bcnt[i], h[i]);
}

__global__ void k_bscan(const unsigned* __restrict__ bcnt, unsigned* __restrict__ bbase,
                        unsigned* __restrict__ bcur, int nb, int tot){
  __shared__ unsigned s[512];
  int t = threadIdx.x;
  unsigned v = (t < nb) ? bcnt[t] : 0u;
  s[t] = v; __syncthreads();
  for (int off = 1; off < 512; off <<= 1){
    unsigned x = (t >= off) ? s[t - off] : 0u; __syncthreads();
    s[t] += x; __syncthreads();
  }
  if (t < nb){ unsigned b = s[t] - v; bbase[t] = b; bcur[t] = b; }
  if (t == 0) bbase[nb] = (unsigned)tot;
}

__global__ __launch_bounds__(256) void k_binscat(const int* __restrict__ ei, int E, int N, int nb,
    unsigned* __restrict__ bcur, unsigned* __restrict__ staged){
  __shared__ unsigned sd[8192];
  __shared__ unsigned hist[512];
  __shared__ unsigned runb[512];
  const int tot = E + N;
  for (int i = threadIdx.x; i < nb; i += 256) hist[i] = 0;
  __syncthreads();
  int base = blockIdx.x * 8192;
  #pragma unroll 4
  for (int j = 0; j < 32; j++){
    int idx = threadIdx.x + j * 256;
    int e = base + idx;
    unsigned d = 0xFFFFFFFFu;
    if (e < tot) d = (e < E) ? (unsigned)ei[E + e] : (unsigned)(e - E);
    sd[idx] = d;
    if (d != 0xFFFFFFFFu) atomicAdd(&hist[d >> 8], 1u);
  }
  __syncthreads();
  for (int i = threadIdx.x; i < nb; i += 256){
    unsigned c = hist[i];
    runb[i] = c ? atomicAdd(&bcur[i], c) : 0u;
    hist[i] = 0;
  }
  __syncthreads();
  #pragma unroll 4
  for (int j = 0; j < 32; j++){
    int idx = threadIdx.x + j * 256;
    unsigned d = sd[idx];
    if (d == 0xFFFFFFFFu) continue;
    int e = base + idx;
    unsigned s = (e < E) ? (unsigned)ei[e] : d;
    unsigned b = d >> 8;
    unsigned pos = runb[b] + atomicAdd(&hist[b], 1u);
    staged[pos] = s | ((d & 255u) << 20);
  }
}

__global__ __launch_bounds__(256) void k_csr(const unsigned* __restrict__ bbase,
    const unsigned* __restrict__ staged, int N,
    unsigned* __restrict__ off_, unsigned* __restrict__ cur, int* __restrict__ srcids){
  __shared__ unsigned cnt[256], scn[256], cnt2[256];
  int b = blockIdx.x, t = threadIdx.x;
  unsigned beg = bbase[b], end = bbase[b + 1];
  cnt[t] = 0; cnt2[t] = 0;
  __syncthreads();
  for (unsigned i = beg + t; i < end; i += 256)
    atomicAdd(&cnt[staged[i] >> 20], 1u);
  __syncthreads();
  unsigned v = cnt[t];
  scn[t] = v; __syncthreads();
  for (int off = 1; off < 256; off <<= 1){
    unsigned x = (t >= off) ? scn[t - off] : 0u; __syncthreads();
    scn[t] += x; __syncthreads();
  }
  unsigned ex = scn[t] - v;
  int d = b * 256 + t;
  if (d < N){ off_[d] = beg + ex; cur[d] = beg + ex + v; }
  cnt[t] = ex;
  __syncthreads();
  for (unsigned i = beg + t; i < end; i += 256){
    unsigned u = staged[i];
    unsigned dl = u >> 20;
    unsigned pos = beg + cnt[dl] + atomicAdd(&cnt2[dl], 1u);
    srcids[pos] = (int)(u & 0xFFFFFu);
  }
}

// ============ W1 prep: Wt_hi/Wt_lo[64][256] bf16 ============
__global__ void k_wprep(const float* __restrict__ W, short* __restrict__ wt_hi,
                        short* __restrict__ wt_lo){
  int i = blockIdx.x * 256 + threadIdx.x;    // 16384
  int k = i >> 6, c = i & 63;
  float v = W[i];
  unsigned u = __float_as_uint(v);
  wt_hi[c * 256 + k] = (short)(u >> 16);
  float lo = v - bfhi_f(v);
  wt_lo[c * 256 + k] = (short)(__float_as_uint(lo) >> 16);
}

// ============ W2 prep: [48][64] bf16 hi/lo (cols 40-47 zero) ============
__global__ void k_w2prep(const float* __restrict__ W2, short* __restrict__ hi,
                         short* __restrict__ lo){
  int i = blockIdx.x * 256 + threadIdx.x;    // 3072
  if (i >= 48 * 64) return;
  int c = i >> 6, k = i & 63;
  float v = (c < 40) ? W2[k * 40 + c] : 0.f;
  unsigned u = __float_as_uint(v);
  hi[c * 64 + k] = (short)(u >> 16);
  float l = v - bfhi_f(v);
  lo[c * 64 + k] = (short)(__float_as_uint(l) >> 16);
}

// ============ GEMM1 via MFMA: global_load_lds staged x, double-buffered, swizzled ============
__global__ __launch_bounds__(256) void k_gemm1_mfma(const float* __restrict__ x,
    const short* __restrict__ wt_hi, const short* __restrict__ wt_lo,
    const float* __restrict__ a1s, const float* __restrict__ a1d,
    unsigned short* __restrict__ h1b, float* __restrict__ as_, float* __restrict__ ad_, int N){
  __shared__ float lds[4][2][1024];          // per-wave: 2 bufs x 16 rows x 64 K fp32 (4KB)
  int lane = threadIdx.x & 63;
  int wv   = threadIdx.x >> 6;
  int r0   = blockIdx.x * 64 + wv * 16;
  if (r0 >= N) return;
  int col16 = lane & 15;
  int kg    = lane >> 4;
  int srl   = lane >> 4;                     // staging: row offset within 4-row group
  int sci   = lane & 15;                     // staging: physical 16B slot

  f32x4 acc[4];
  #pragma unroll
  for (int ct = 0; ct < 4; ct++) acc[ct] = (f32x4){0.f, 0.f, 0.f, 0.f};

  // prologue: stage chunk 0 into buf 0 (4 coalesced 1KB gload_lds per wave)
  #pragma unroll
  for (int ri = 0; ri < 4; ri++){
    int rl = ri * 4 + srl;
    int ci = sci ^ (rl & 7);                 // pre-swizzled global source (m173 / rule 21)
    const float* gsrc = x + (size_t)min(r0 + rl, N - 1) * 256 + ci * 4;
    float* ldst = &lds[wv][0][ri * 256];
    __builtin_amdgcn_global_load_lds((const __attribute__((address_space(1))) void*)(const void*)gsrc,
                                     (__attribute__((address_space(3))) void*)(void*)ldst, 16, 0, 0);
  }

  int buf = 0;
  for (int ch = 0; ch < 4; ch++){
    if (ch < 3){
      #pragma unroll
      for (int ri = 0; ri < 4; ri++){
        int rl = ri * 4 + srl;
        int ci = sci ^ (rl & 7);
        const float* gsrc = x + (size_t)min(r0 + rl, N - 1) * 256 + (ch + 1) * 64 + ci * 4;
        float* ldst = &lds[wv][buf ^ 1][ri * 256];
        __builtin_amdgcn_global_load_lds((const __attribute__((address_space(1))) void*)(const void*)gsrc,
                                         (__attribute__((address_space(3))) void*)(void*)ldst, 16, 0, 0);
      }
      asm volatile("s_waitcnt vmcnt(4)" ::: "memory");   // chunk ch done; next-chunk loads in flight
    } else {
      asm volatile("s_waitcnt vmcnt(0)" ::: "memory");
    }
    __builtin_amdgcn_sched_barrier(0);

    const float* wb = &lds[wv][buf][0];
    #pragma unroll
    for (int kt = 0; kt < 2; kt++){
      int b16 = kt * 8 + kg * 2;
      int swz = col16 & 7;
      float4 v0 = *(const float4*)(wb + col16 * 64 + (((b16 + 0) ^ swz) << 2));
      float4 v1 = *(const float4*)(wb + col16 * 64 + (((b16 + 1) ^ swz) << 2));
      unsigned u[8] = {__float_as_uint(v0.x), __float_as_uint(v0.y), __float_as_uint(v0.z), __float_as_uint(v0.w),
                       __float_as_uint(v1.x), __float_as_uint(v1.y), __float_as_uint(v1.z), __float_as_uint(v1.w)};
      union { bf16x8 v; unsigned u[4]; } ahi, alo;
      #pragma unroll
      for (int j = 0; j < 4; j++)
        ahi.u[j] = __builtin_amdgcn_perm(u[2*j+1], u[2*j], 0x07060302);
      float lo[8];
      lo[0] = v0.x - bfhi_f(v0.x); lo[1] = v0.y - bfhi_f(v0.y);
      lo[2] = v0.z - bfhi_f(v0.z); lo[3] = v0.w - bfhi_f(v0.w);
      lo[4] = v1.x - bfhi_f(v1.x); lo[5] = v1.y - bfhi_f(v1.y);
      lo[6] = v1.z - bfhi_f(v1.z); lo[7] = v1.w - bfhi_f(v1.w);
      #pragma unroll
      for (int j = 0; j < 4; j++)
        alo.u[j] = __builtin_amdgcn_perm(__float_as_uint(lo[2*j+1]), __float_as_uint(lo[2*j]), 0x07060302);

      int ktg = ch * 2 + kt;
      #pragma unroll
      for (int ct = 0; ct < 4; ct++){
        int wcol = ct * 16 + col16;
        const bf16x8 bhi = *(const bf16x8*)(wt_hi + wcol * 256 + ktg * 32 + kg * 8);
        const bf16x8 blo = *(const bf16x8*)(wt_lo + wcol * 256 + ktg * 32 + kg * 8);
        acc[ct] = __builtin_amdgcn_mfma_f32_16x16x32_bf16(ahi.v, bhi, acc[ct], 0, 0, 0);
        acc[ct] = __builtin_amdgcn_mfma_f32_16x16x32_bf16(ahi.v, blo, acc[ct], 0, 0, 0);
        acc[ct] = __builtin_amdgcn_mfma_f32_16x16x32_bf16(alo.v, bhi, acc[ct], 0, 0, 0);
      }
    }
    buf ^= 1;
  }

  float cs[4], cd[4];
  #pragma unroll
  for (int ct = 0; ct < 4; ct++){ cs[ct] = a1s[ct * 16 + col16]; cd[ct] = a1d[ct * 16 + col16]; }
  #pragma unroll
  for (int r = 0; r < 4; r++){
    int rr = r0 + kg * 4 + r;
    bool ok = rr < N;
    #pragma unroll
    for (int ct = 0; ct < 4; ct++){
      float v = acc[ct][r];
      if (ok) h1b[(size_t)rr * 64 + ct * 16 + col16] = f2bf(v);
      float s = v * cs[ct];
      float t = v * cd[ct];
      s += __shfl_xor(s, 1, 64); s += __shfl_xor(s, 2, 64); s += __shfl_xor(s, 4, 64);
      t += __shfl_xor(t, 1, 64); t += __shfl_xor(t, 2, 64); t += __shfl_xor(t, 4, 64);
      if (ok && (col16 & 7) == 0){
        int head = ct * 2 + (col16 >> 3);
        as_[(size_t)rr * 8 + head] = s;
        ad_[(size_t)rr * 8 + head] = t;
      }
    }
  }
}

// ============ layer-1 per-dst gather: staged srcids, MLP-4 channel phase ============
__global__ __launch_bounds__(256) void k_gat1(const unsigned* __restrict__ off_, const unsigned* __restrict__ cur,
    const int* __restrict__ srcids, const float* __restrict__ as_, const float* __restrict__ ad_,
    const unsigned short* __restrict__ h1b, const float* __restrict__ b1,
    unsigned short* __restrict__ out1b, int N){
  int lane = threadIdx.x & 63;
  int wv   = threadIdx.x >> 6;
  int d    = blockIdx.x * 4 + wv;
  if (d >= N) return;
  __shared__ float lds_p[4][64 * 8];
  __shared__ int   lds_s[4][64];
  float* lp = lds_p[wv];
  int*   ls = lds_s[wv];
  unsigned beg = off_[d], fin = cur[d];

  int e8 = lane >> 3, h = lane & 7;                  // exp-phase layout
  int c0 = lane & 31, pe = lane >> 5, hh = c0 >> 2;  // channel-phase layout
  float adh = ad_[(size_t)d * 8 + h];
  float psacc = 0.f, accx = 0.f, accy = 0.f;

  for (unsigned base = beg; base < fin; base += 64){
    int nthis = (int)min(64u, fin - base);
    unsigned i = base + lane;
    ls[lane] = (i < fin) ? srcids[i] : 0;            // one coalesced stage
    asm volatile("s_waitcnt lgkmcnt(0)" ::: "memory");
    __builtin_amdgcn_sched_barrier(0);
    for (int j = 0; j < nthis; j += 8){
      int eloc = j + e8;
      int s = ls[eloc];
      float p = 0.f;
      if (eloc < nthis) p = __expf(lrelu(as_[(size_t)s * 8 + h] + adh));
      lp[eloc * 8 + h] = p;
      psacc += p;
    }
    asm volatile("s_waitcnt lgkmcnt(0)" ::: "memory");
    __builtin_amdgcn_sched_barrier(0);
    for (int e = 0; e < nthis; e += 8){
      int e0 = e + pe, e1 = e + 2 + pe, e2 = e + 4 + pe, e3 = e + 6 + pe;
      float p0 = lp[e0 * 8 + hh], p1 = lp[e1 * 8 + hh];
      float p2 = lp[e2 * 8 + hh], p3 = lp[e3 * 8 + hh];
      int s0 = ls[e0], s1 = ls[e1], s2 = ls[e2], s3 = ls[e3];
      unsigned u0 = *(const unsigned*)(h1b + (size_t)s0 * 64 + c0 * 2);
      unsigned u1 = *(const unsigned*)(h1b + (size_t)s1 * 64 + c0 * 2);
      unsigned u2 = *(const unsigned*)(h1b + (size_t)s2 * 64 + c0 * 2);
      unsigned u3 = *(const unsigned*)(h1b + (size_t)s3 * 64 + c0 * 2);
      accx = fmaf(p0, __uint_as_float(u0 << 16), accx);
      accy = fmaf(p0, __uint_as_float(u0 & 0xFFFF0000u), accy);
      accx = fmaf(p1, __uint_as_float(u1 << 16), accx);
      accy = fmaf(p1, __uint_as_float(u1 & 0xFFFF0000u), accy);
      accx = fmaf(p2, __uint_as_float(u2 << 16), accx);
      accy = fmaf(p2, __uint_as_float(u2 & 0xFFFF0000u), accy);
      accx = fmaf(p3, __uint_as_float(u3 << 16), accx);
      accy = fmaf(p3, __uint_as_float(u3 & 0xFFFF0000u), accy);
    }
    asm volatile("" ::: "memory");
  }
  float den = psacc;
  den += __shfl_xor(den, 8, 64);
  den += __shfl_xor(den, 16, 64);
  den += __shfl_xor(den, 32, 64);
  float mydenv = __shfl(den, hh, 64);
  accx += __shfl_xor(accx, 32, 64);
  accy += __shfl_xor(accy, 32, 64);
  if (lane < 32){
    int ch = lane * 2;
    float v0 = accx / mydenv + b1[ch];
    float v1 = accy / mydenv + b1[ch + 1];
    ushort2 o;
    o.x = f2bf(v0 > 0.f ? v0 : 0.f);
    o.y = f2bf(v1 > 0.f ? v1 : 0.f);
    *(ushort2*)(out1b + (size_t)d * 64 + ch) = o;
  }
}

// ============ GEMM2 via MFMA (bf16 A, hi/lo B) + fused alpha2 ============
__global__ __launch_bounds__(256) void k_gemm2m(const unsigned short* __restrict__ out1b,
    const short* __restrict__ wt2_hi, const short* __restrict__ wt2_lo,
    const float* __restrict__ a2s, const float* __restrict__ a2d,
    unsigned short* __restrict__ h2b, float* __restrict__ as_, float* __restrict__ ad_, int N){
  int lane = threadIdx.x & 63;
  int wv   = threadIdx.x >> 6;
  int r0   = blockIdx.x * 64 + wv * 16;
  if (r0 >= N) return;
  int col16 = lane & 15;
  int kg    = lane >> 4;
  const unsigned short* ar = out1b + (size_t)min(r0 + col16, N - 1) * 64 + kg * 8;

  f32x4 acc[3];
  #pragma unroll
  for (int ct = 0; ct < 3; ct++) acc[ct] = (f32x4){0.f, 0.f, 0.f, 0.f};

  #pragma unroll
  for (int kt = 0; kt < 2; kt++){
    const bf16x8 a = *(const bf16x8*)(ar + kt * 32);
    #pragma unroll
    for (int ct = 0; ct < 3; ct++){
      int wcol = ct * 16 + col16;
      const bf16x8 bhi = *(const bf16x8*)(wt2_hi + wcol * 64 + kt * 32 + kg * 8);
      const bf16x8 blo = *(const bf16x8*)(wt2_lo + wcol * 64 + kt * 32 + kg * 8);
      acc[ct] = __builtin_amdgcn_mfma_f32_16x16x32_bf16(a, bhi, acc[ct], 0, 0, 0);
      acc[ct] = __builtin_amdgcn_mfma_f32_16x16x32_bf16(a, blo, acc[ct], 0, 0, 0);
    }
  }

  float cs[3], cd[3];
  #pragma unroll
  for (int ct = 0; ct < 3; ct++){
    int col = ct * 16 + col16;
    bool okc = col < 40;
    cs[ct] = okc ? a2s[col] : 0.f;
    cd[ct] = okc ? a2d[col] : 0.f;
  }
  #pragma unroll
  for (int r = 0; r < 4; r++){
    int rr = r0 + kg * 4 + r;
    bool ok = rr < N;
    float s = 0.f, t = 0.f;
    #pragma unroll
    for (int ct = 0; ct < 3; ct++){
      s = fmaf(acc[ct][r], cs[ct], s);
      t = fmaf(acc[ct][r], cd[ct], t);
      int col = ct * 16 + col16;
      if (ok && col < 40) h2b[(size_t)rr * 40 + col] = f2bf(acc[ct][r]);
    }
    s += __shfl_xor(s, 1, 64); s += __shfl_xor(s, 2, 64);
    s += __shfl_xor(s, 4, 64); s += __shfl_xor(s, 8, 64);
    t += __shfl_xor(t, 1, 64); t += __shfl_xor(t, 2, 64);
    t += __shfl_xor(t, 4, 64); t += __shfl_xor(t, 8, 64);
    if (ok && col16 == 0){ as_[rr] = s; ad_[rr] = t; }
  }
}

// ============ layer-2 per-dst gather (H=1, C=40), MLP-4 + fused bias+log_softmax ============
__global__ __launch_bounds__(256) void k_gat2(const unsigned* __restrict__ off_, const unsigned* __restrict__ cur,
    const int* __restrict__ srcids, const float* __restrict__ as_, const float* __restrict__ ad_,
    const unsigned short* __restrict__ h2b, const float* __restrict__ b2, float* __restrict__ out, int N){
  int lane = threadIdx.x & 63;
  int wv   = threadIdx.x >> 6;
  int d    = blockIdx.x * 4 + wv;
  if (d >= N) return;
  __shared__ float lds_p[4][64];
  __shared__ int   lds_s[4][64];
  float* lp = lds_p[wv];
  int*   ls = lds_s[wv];
  unsigned beg = off_[d], fin = cur[d];
  float add = ad_[d];

  int c0 = lane & 31;
  int pe = lane >> 5;
  int idx = c0 < 20 ? c0 : 19;
  float ps = 0.f, accx = 0.f, accy = 0.f;

  for (unsigned base = beg; base < fin; base += 64){
    unsigned i = base + lane;
    int nthis = (int)min(64u, fin - base);
    if (i < fin){
      int s = srcids[i];
      float p = __expf(lrelu(as_[s] + add));
      ps += p; ls[lane] = s; lp[lane] = p;
    } else { ls[lane] = 0; lp[lane] = 0.f; }
    asm volatile("s_waitcnt lgkmcnt(0)" ::: "memory");
    __builtin_amdgcn_sched_barrier(0);
    for (int e = 0; e < nthis; e += 8){
      int e0 = e + pe, e1 = e + 2 + pe, e2 = e + 4 + pe, e3 = e + 6 + pe;
      float p0 = lp[e0], p1 = lp[e1], p2 = lp[e2], p3 = lp[e3];
      int s0 = ls[e0], s1 = ls[e1], s2 = ls[e2], s3 = ls[e3];
      unsigned u0 = *(const unsigned*)(h2b + (size_t)s0 * 40 + idx * 2);
      unsigned u1 = *(const unsigned*)(h2b + (size_t)s1 * 40 + idx * 2);
      unsigned u2 = *(const unsigned*)(h2b + (size_t)s2 * 40 + idx * 2);
      unsigned u3 = *(const unsigned*)(h2b + (size_t)s3 * 40 + idx * 2);
      accx = fmaf(p0, __uint_as_float(u0 << 16), accx);
      accy = fmaf(p0, __uint_as_float(u0 & 0xFFFF0000u), accy);
      accx = fmaf(p1, __uint_as_float(u1 << 16), accx);
      accy = fmaf(p1, __uint_as_float(u1 & 0xFFFF0000u), accy);
      accx = fmaf(p2, __uint_as_float(u2 << 16), accx);
      accy = fmaf(p2, __uint_as_float(u2 & 0xFFFF0000u), accy);
      accx = fmaf(p3, __uint_as_float(u3 << 16), accx);
      accy = fmaf(p3, __uint_as_float(u3 & 0xFFFF0000u), accy);
    }
    asm volatile("" ::: "memory");
  }
  ps = wred_sum(ps);
  accx += __shfl_xor(accx, 32, 64);
  accy += __shfl_xor(accy, 32, 64);

  float v0 = accx / ps + b2[idx * 2];
  float v1 = accy / ps + b2[idx * 2 + 1];
  bool act = (c0 < 20);
  float mx = act ? fmaxf(v0, v1) : -INFINITY;
  #pragma unroll
  for (int o = 16; o; o >>= 1) mx = fmaxf(mx, __shfl_xor(mx, o, 64));
  float exs = act ? (__expf(v0 - mx) + __expf(v1 - mx)) : 0.f;
  #pragma unroll
  for (int o = 16; o; o >>= 1) exs += __shfl_xor(exs, o, 64);
  float lse = mx + logf(exs);
  if (lane < 20){
    float2 o2; o2.x = v0 - lse; o2.y = v1 - lse;
    *(float2*)(out + (size_t)d * 40 + lane * 2) = o2;
  }
}

extern "C" void kernel_launch(void* const* d_in, const int* in_sizes, int n_in,
                              void* d_out, int out_size, void* d_ws, size_t ws_size,
                              hipStream_t stream){
  const float* x   = (const float*)d_in[0];
  const int*   ei  = (const int*)d_in[1];
  const float* W1  = (const float*)d_in[2];
  const float* a1s = (const float*)d_in[3];
  const float* a1d = (const float*)d_in[4];
  const float* b1  = (const float*)d_in[5];
  const float* W2  = (const float*)d_in[6];
  const float* a2s = (const float*)d_in[7];
  const float* a2d = (const float*)d_in[8];
  const float* b2  = (const float*)d_in[9];
  float* out = (float*)d_out;

  const int N = in_sizes[0] / 256;
  const int E = in_sizes[1] / 2;
  const int tot = E + N;
  const int nb  = (N + 255) >> 8;

  float* ws = (float*)d_ws;
  size_t o = 0;
  float* as1  = ws + o; o += (size_t)N * 8;
  float* ad1  = ws + o; o += (size_t)N * 8;
  unsigned short* out1b = (unsigned short*)(ws + o); o += (size_t)N * 32;  // aliases `staged`
  unsigned short* h1b   = (unsigned short*)(ws + o); o += (size_t)N * 32;
  unsigned short* h2b   = (unsigned short*)(ws + o); o += (size_t)N * 20;
  unsigned* off_ = (unsigned*)(ws + o); o += (size_t)N;
  unsigned* cur  = (unsigned*)(ws + o); o += (size_t)N;
  int* srcids    = (int*)(ws + o);      o += (size_t)tot;
  short* wt_hi   = (short*)(ws + o);    o += 8192;   // 16384 bf16
  short* wt_lo   = (short*)(ws + o);    o += 8192;
  short* wt2_hi  = (short*)(ws + o);    o += 1536;   // 3072 bf16 (48x64)
  short* wt2_lo  = (short*)(ws + o);    o += 1536;
  unsigned* bcnt  = (unsigned*)(ws + o); o += nb;
  unsigned* bbase = (unsigned*)(ws + o); o += nb + 1;
  unsigned* bcur  = (unsigned*)(ws + o); o += nb;
  unsigned* staged = (unsigned*)out1b;
  float* as2 = as1;
  float* ad2 = ad1;

  const int cb = (tot + 8191) / 8192;

  hipMemsetAsync(bcnt, 0, sizeof(unsigned) * (size_t)nb, stream);

  // bucketed CSR build
  k_bincnt <<<cb, 256, 0, stream>>>(ei, E, N, nb, bcnt);
  k_bscan  <<<1, 512, 0, stream>>>(bcnt, bbase, bcur, nb, tot);
  k_binscat<<<cb, 256, 0, stream>>>(ei, E, N, nb, bcur, staged);
  k_csr    <<<nb, 256, 0, stream>>>(bbase, staged, N, off_, cur, srcids);

  // weight prep
  k_wprep <<<64, 256, 0, stream>>>(W1, wt_hi, wt_lo);
  k_w2prep<<<12, 256, 0, stream>>>(W2, wt2_hi, wt2_lo);

  // layer 1
  k_gemm1_mfma<<<(N + 63) / 64, 256, 0, stream>>>(x, wt_hi, wt_lo, a1s, a1d, h1b, as1, ad1, N);
  k_gat1 <<<(N + 3) / 4, 256, 0, stream>>>(off_, cur, srcids, as1, ad1, h1b, b1, out1b, N);

  // layer 2
  k_gemm2m<<<(N + 63) / 64, 256, 0, stream>>>(out1b, wt2_hi, wt2_lo, a2s, a2d, h2b, as2, ad2, N);
  k_gat2  <<<(N + 3) / 4, 256, 0, stream>>>(off_, cur, srcids, as2, ad2, h2b, b2, out, N);
}